// Round 12
// baseline (13067.535 us; speedup 1.0000x reference)
//
#include <hip/hip_runtime.h>
#include <hip/hip_cooperative_groups.h>
#include <math.h>

#define NROWS 2048
#define KNEI  8
#define LSEQ  64
#define HD    512
#define HD4   128
#define LATD  128
#define NHPN  4
#define NNUC  5

typedef __attribute__((ext_vector_type(8))) short s8b;   // 8 bf16 (16B)
typedef __attribute__((ext_vector_type(4))) short s4b;   // 4 bf16 (8B)
typedef __attribute__((ext_vector_type(4))) float f4;    // MFMA acc

#define MFMA16(a,b,c) __builtin_amdgcn_mfma_f32_16x16x32_bf16(a,b,c,0,0,0)

__device__ __forceinline__ f4 f4zero(){ f4 z; z[0]=0.f; z[1]=0.f; z[2]=0.f; z[3]=0.f; return z; }
__device__ __forceinline__ float sigf(float x){ return __fdividef(1.0f, 1.0f + __expf(-x)); }
__device__ __forceinline__ float tanhf_fast(float x){
  float e = __expf(-2.0f*fabsf(x));
  float t = __fdividef(1.0f - e, 1.0f + e);
  return x >= 0.f ? t : -t;
}
__device__ __forceinline__ unsigned short f2bf(float x){
  union{float f; unsigned u;} v; v.f = x;
  unsigned r = (v.u + 0x7FFFu + ((v.u>>16)&1u)) >> 16;
  return (unsigned short)r;
}
__device__ __forceinline__ float bf2f(unsigned short u){
  union{unsigned x; float f;} v; v.x = ((unsigned)u)<<16; return v.f;
}
__device__ __forceinline__ void add4(float4& a, float4 b){ a.x+=b.x; a.y+=b.y; a.z+=b.z; a.w+=b.w; }

__device__ __forceinline__ void dma16(const short* g, const short* l){
  __builtin_amdgcn_global_load_lds(
      (const __attribute__((address_space(1))) void*)(unsigned long long)g,
      (__attribute__((address_space(3))) void*)(unsigned long long)l,
      16, 0, 0);
}

// ---------------- prep kernels ----------------

__global__ void transpose_w(const float* __restrict__ src, float* __restrict__ dst,
                            int src_cols, int col_off, int nh){
  int idx = blockIdx.x*256 + threadIdx.x;
  if (idx >= nh*HD) return;
  int h = idx / HD, o = idx - h*HD;
  dst[idx] = src[o*src_cols + col_off + h];
}

// B-frag layout (per 16x16x32 tile, 1KB): dst[tile*512 + l*8 + j] = W[n][k]
__global__ void fragprep_k(const float* __restrict__ W, short* __restrict__ dst,
                           int src_cols, int col_off){
  int idx = blockIdx.x*256 + threadIdx.x;
  if (idx >= HD*HD) return;
  int j = idx&7, l = (idx>>3)&63, tile = idx>>9;
  int kc = tile&15, ot = tile>>4;
  int row = ot*16 + (l&15), k = kc*32 + (l>>4)*8 + j;
  dst[idx] = (short)f2bf(W[(size_t)row*src_cols + col_off + k]);
}

// wxb[c*HD + n] = W[n][c] + b[n]   (nc codes)
__global__ void wxbprep2_k(const float* __restrict__ W, const float* __restrict__ b,
                           float* __restrict__ dst, int src_cols, int nc){
  int idx = blockIdx.x*256 + threadIdx.x;
  if (idx >= nc*HD) return;
  int c = idx/HD, n = idx - c*HD;
  dst[idx] = W[(size_t)n*src_cols + c] + b[n];
}

// latp[n][o] = b_nl[o] + sum_q gl[n][q]*wtlat[q*HD+o]
__global__ __launch_bounds__(512) void latp_k(const float* __restrict__ gl, const float* __restrict__ wtlat,
                     const float* __restrict__ bnl, float* __restrict__ latp){
  __shared__ float gls[16][LATD];
  int b = blockIdx.x, t = threadIdx.x;
  for (int i=t;i<16*LATD;i+=512) gls[i/LATD][i%LATD] = gl[(size_t)(b*16)*LATD + i];
  __syncthreads();
  float acc[16];
  float bv = bnl[t];
  #pragma unroll
  for (int r=0;r<16;++r) acc[r]=bv;
  for (int q=0;q<LATD;++q){
    float wv = wtlat[(size_t)q*HD + t];
    #pragma unroll
    for (int r=0;r<16;++r) acc[r] = fmaf(gls[r][q], wv, acc[r]);
  }
  #pragma unroll
  for (int r=0;r<16;++r) latp[(size_t)(b*16+r)*HD + t] = acc[r];
}

// sumh = h_nei.sum(k): fp32 + bf16 copies; also bf16 copy of full h_nei (hnB).
__global__ void sumcast_k(const float* __restrict__ h_nei,
                          float* __restrict__ sumhF, short* __restrict__ sumhB,
                          short* __restrict__ hnB){
  int idx = blockIdx.x*512 + threadIdx.x;
  int n = idx >> 7, c4 = idx & 127;
  const float4* hn4 = (const float4*)h_nei;
  size_t base = (size_t)n*KNEI*HD4 + c4;
  float4 s = make_float4(0.f,0.f,0.f,0.f);
  #pragma unroll
  for (int k=0;k<KNEI;++k){
    float4 v = hn4[base + (size_t)k*HD4];
    add4(s, v);
    s4b pb;
    pb[0]=(short)f2bf(v.x); pb[1]=(short)f2bf(v.y); pb[2]=(short)f2bf(v.z); pb[3]=(short)f2bf(v.w);
    ((s4b*)hnB)[(size_t)(n*KNEI + k)*HD4 + c4] = pb;
  }
  ((float4*)sumhF)[(size_t)n*HD4 + c4] = s;
  s4b p;
  p[0]=(short)f2bf(s.x); p[1]=(short)f2bf(s.y); p[2]=(short)f2bf(s.z); p[3]=(short)f2bf(s.w);
  ((s4b*)sumhB)[(size_t)n*HD4 + c4] = p;
}

// ---------------- GraphGRU MFMA GEMMs ----------------
__global__ __launch_bounds__(512) void ggru_gemm_k(
    int mode,
    const short* __restrict__ frag,
    const short* __restrict__ A,
    const int* __restrict__ hpn_idx,
    const float* __restrict__ bias_tab,
    const float* __restrict__ sumhF, const float* __restrict__ zF_in,
    const float* __restrict__ w_topo,
    float* __restrict__ zF_out,
    float* __restrict__ hF, short* __restrict__ hB,
    float* __restrict__ topo_p)
{
  __shared__ __align__(16) short stage[16][4096];
  __shared__ int codes_s[32];
  const int tt = threadIdx.x, l = tt&63, w = tt>>6, lm = l&15, g = l>>4;
  const int rt = blockIdx.x, row0 = rt*32, cg = blockIdx.y;
  if (tt<32) codes_s[tt] = hpn_idx[row0+tt];
  const int mt = w>>2, ntp = w&3;
  const short* gsrc = frag + ((size_t)(cg*8 + w)*16)*512 + (size_t)l*8;
  #pragma unroll
  for (int kc=0;kc<8;++kc) dma16(gsrc + (size_t)kc*512, &stage[kc][w*512 + l*8]);
  s8b af[16];
  {
    const s8b* arow = (const s8b*)(A + (size_t)(row0 + mt*16 + lm)*HD);
    #pragma unroll
    for (int kc=0;kc<16;++kc) af[kc] = arow[kc*4 + g];
  }
  asm volatile("s_waitcnt vmcnt(0)" ::: "memory");
  __syncthreads();
  #pragma unroll
  for (int kc=8;kc<16;++kc) dma16(gsrc + (size_t)kc*512, &stage[kc][w*512 + l*8]);
  f4 acc[2]; acc[0]=f4zero(); acc[1]=f4zero();
  #pragma unroll
  for (int kc=0;kc<8;++kc){
    #pragma unroll
    for (int i2=0;i2<2;++i2){
      s8b b = ((const s8b*)&stage[kc][(ntp*2+i2)*512])[l];
      acc[i2] = MFMA16(af[kc], b, acc[i2]);
    }
  }
  asm volatile("s_waitcnt vmcnt(0)" ::: "memory");
  __syncthreads();
  #pragma unroll
  for (int kc=8;kc<16;++kc){
    #pragma unroll
    for (int i2=0;i2<2;++i2){
      s8b b = ((const s8b*)&stage[kc][(ntp*2+i2)*512])[l];
      acc[i2] = MFMA16(af[kc], b, acc[i2]);
    }
  }
  if (mode==0){
    #pragma unroll
    for (int i2=0;i2<2;++i2){
      const int col = cg*128 + (ntp*2+i2)*16 + lm;
      #pragma unroll
      for (int q=0;q<4;++q){
        const int r = mt*16 + g*4 + q;
        zF_out[(size_t)(row0+r)*HD + col] = sigf(acc[i2][q] + bias_tab[codes_s[r]*HD + col]);
      }
    }
  } else if (mode==1){
    #pragma unroll
    for (int i2=0;i2<2;++i2){
      const int col = cg*128 + (ntp*2+i2)*16 + lm;
      #pragma unroll
      for (int q=0;q<4;++q){
        const int r = mt*16 + g*4 + q;
        const size_t idx = (size_t)(row0+r)*HD + col;
        float pre = tanhf_fast(acc[i2][q] + bias_tab[codes_s[r]*HD + col]);
        float zv = zF_in[idx];
        float m = (1.f - zv)*sumhF[idx] + zv*pre;
        hF[idx] = m;
        hB[idx] = (short)f2bf(m);
      }
    }
  } else {
    float p[4];
    #pragma unroll
    for (int q=0;q<4;++q) p[q]=0.f;
    #pragma unroll
    for (int i2=0;i2<2;++i2){
      const int col = cg*128 + (ntp*2+i2)*16 + lm;
      float wv = w_topo[col];
      float bnl = bias_tab[col];
      #pragma unroll
      for (int q=0;q<4;++q){
        float hid = fmaxf(acc[i2][q] + bnl, 0.f);
        p[q] = fmaf(hid, wv, p[q]);
      }
    }
    #pragma unroll
    for (int s=1;s<16;s<<=1)
      #pragma unroll
      for (int q=0;q<4;++q) p[q] += __shfl_xor(p[q], s);
    if (lm==0){
      #pragma unroll
      for (int q=0;q<4;++q)
        topo_p[(size_t)(cg*4+ntp)*NROWS + row0 + mt*16 + g*4 + q] = p[q];
    }
  }
}

// r gate: [16384,512] x Ur^T with in-register k-reduction -> sum_gated bf16.
__global__ __launch_bounds__(512) void ggru_r_k(
    const short* __restrict__ fUr,
    const short* __restrict__ hnB,
    const int* __restrict__ hpn_idx,
    const float* __restrict__ wxbr_mp,
    short* __restrict__ sgB)
{
  __shared__ __align__(16) short stage[16][4096];
  __shared__ int codes_s[16];
  const int tt = threadIdx.x, l = tt&63, w = tt>>6, lm = l&15, g = l>>4;
  const int row0 = blockIdx.x*128, cg = blockIdx.y;
  if (tt<16) codes_s[tt] = hpn_idx[(row0>>3) + tt];
  const short* gsrc = fUr + ((size_t)(cg*8 + w)*16)*512 + (size_t)l*8;
  #pragma unroll
  for (int kc=0;kc<8;++kc) dma16(gsrc + (size_t)kc*512, &stage[kc][w*512 + l*8]);
  s8b af[16];
  {
    const s8b* arow = (const s8b*)(hnB + (size_t)(row0 + w*16 + lm)*HD);
    #pragma unroll
    for (int kc=0;kc<16;++kc) af[kc] = arow[kc*4 + g];
  }
  asm volatile("s_waitcnt vmcnt(0)" ::: "memory");
  __syncthreads();
  #pragma unroll
  for (int kc=8;kc<16;++kc) dma16(gsrc + (size_t)kc*512, &stage[kc][w*512 + l*8]);
  f4 acc[8];
  #pragma unroll
  for (int i=0;i<8;++i) acc[i]=f4zero();
  #pragma unroll
  for (int kc=0;kc<8;++kc){
    #pragma unroll
    for (int ot=0;ot<8;++ot){
      s8b b = ((const s8b*)&stage[kc][ot*512])[l];
      acc[ot] = MFMA16(af[kc], b, acc[ot]);
    }
  }
  asm volatile("s_waitcnt vmcnt(0)" ::: "memory");
  __syncthreads();
  #pragma unroll
  for (int kc=8;kc<16;++kc){
    #pragma unroll
    for (int ot=0;ot<8;++ot){
      s8b b = ((const s8b*)&stage[kc][ot*512])[l];
      acc[ot] = MFMA16(af[kc], b, acc[ot]);
    }
  }
  const int nloc = w*2 + (g>>1);
  const int code = codes_s[nloc];
  #pragma unroll
  for (int ot=0;ot<8;++ot){
    const int col = cg*128 + ot*16 + lm;
    float part = 0.f;
    #pragma unroll
    for (int q=0;q<4;++q){
      const int lr = w*16 + g*4 + q;
      float rv = sigf(acc[ot][q] + wxbr_mp[code*HD + col]);
      part += rv * bf2f((unsigned short)hnB[(size_t)(row0+lr)*HD + col]);
    }
    part += __shfl_xor(part, 16);
    if ((g&1)==0){
      const int node = (row0>>3) + nloc;
      sgB[(size_t)node*HD + col] = (short)f2bf(part);
    }
  }
}

// ---------------- persistent cooperative scan ----------------
struct ScanArgs {
  const int* nuc_idx;
  const short* fz; const short* fr; const short* fnuc; const short* fh;
  short* hB; float* hF;
  const float* wxbz; const float* wxbr; const float* wxbh;
  const float* latp; const float* w_nuc; const float* b_nuc;
  float* zF; short* ghB; float* nucp; float* out_nuc;
};

// 256 blocks x 512 thr, 1/CU (128KB LDS). Blocks 0..191: z/r/nuc tiles
// (mat = bid>>6, rt = (bid&63)>>2 -> 128 rows, cg = bid&3 -> 128 cols).
// Blocks 192..255: cand tiles (rt,cg same split). Weight slice staged ONCE.
__global__ __launch_bounds__(512, 1) void scan_coop_k(ScanArgs a){
  namespace cg_ns = cooperative_groups;
  cg_ns::grid_group grid = cg_ns::this_grid();
  __shared__ __align__(16) short stage[16][4096];
  __shared__ int codes_s[128];
  const int tt = threadIdx.x, l = tt&63, w = tt>>6, lm = l&15, g = l>>4;
  const int bid = blockIdx.x;
  const bool isA = bid < 192;
  int mat = 0, row0, cgi;
  const short* frag;
  if (isA){
    mat = bid >> 6;
    int rem = bid & 63;
    row0 = (rem>>2)*128; cgi = rem&3;
    frag = (mat==0)?a.fz:((mat==1)?a.fr:a.fnuc);
  } else {
    int rem = bid - 192;
    row0 = (rem>>2)*128; cgi = rem&3;
    frag = a.fh;
  }
  const int colb = cgi*128;
  // one-time stage of this block's 128KB weight slice
  {
    const short* gsrc = frag + ((size_t)(cgi*8 + w)*16)*512 + (size_t)l*8;
    #pragma unroll
    for (int kc=0;kc<16;++kc) dma16(gsrc + (size_t)kc*512, &stage[kc][w*512 + l*8]);
    asm volatile("s_waitcnt vmcnt(0)" ::: "memory");
    __syncthreads();
  }

  for (int t=0; t<LSEQ; ++t){
    if (isA && !(t==0 && mat==2)){
      if (tt<128) codes_s[tt] = a.nuc_idx[(size_t)(row0+tt)*LSEQ + t];
      s8b af[16];
      const s8b* hrow = (const s8b*)(a.hB + (size_t)(row0 + w*16 + lm)*HD);
      #pragma unroll
      for (int kc=0;kc<16;++kc) af[kc] = hrow[kc*4 + g];
      __syncthreads();
      f4 acc[8];
      #pragma unroll
      for (int i=0;i<8;++i) acc[i]=f4zero();
      #pragma unroll
      for (int kc=0;kc<16;++kc){
        #pragma unroll
        for (int ot=0;ot<8;++ot){
          s8b b = ((const s8b*)&stage[kc][ot*512])[l];
          acc[ot] = MFMA16(af[kc], b, acc[ot]);
        }
      }
      if (mat==0){
        #pragma unroll
        for (int ot=0;ot<8;++ot){
          const int col = colb + ot*16 + lm;
          #pragma unroll
          for (int q=0;q<4;++q){
            const int r = w*16 + g*4 + q;
            a.zF[(size_t)(row0+r)*HD + col] = sigf(acc[ot][q] + a.wxbz[codes_s[r]*HD + col]);
          }
        }
      } else if (mat==1){
        #pragma unroll
        for (int ot=0;ot<8;++ot){
          const int col = colb + ot*16 + lm;
          #pragma unroll
          for (int q=0;q<4;++q){
            const int r = w*16 + g*4 + q;
            float rv = sigf(acc[ot][q] + a.wxbr[codes_s[r]*HD + col]);
            a.ghB[(size_t)(row0+r)*HD + col] = (short)f2bf(rv * a.hF[(size_t)(row0+r)*HD + col]);
          }
        }
      } else {
        float p[4][NNUC];
        #pragma unroll
        for (int q=0;q<4;++q)
          #pragma unroll
          for (int j=0;j<NNUC;++j) p[q][j]=0.f;
        #pragma unroll
        for (int ot=0;ot<8;++ot){
          const int col = colb + ot*16 + lm;
          #pragma unroll
          for (int q=0;q<4;++q){
            const int r = w*16 + g*4 + q;
            float hid = fmaxf(acc[ot][q] + a.latp[(size_t)(row0+r)*HD + col], 0.f);
            #pragma unroll
            for (int j=0;j<NNUC;++j) p[q][j] = fmaf(hid, a.w_nuc[(size_t)j*HD + col], p[q][j]);
          }
        }
        #pragma unroll
        for (int s=1;s<16;s<<=1)
          #pragma unroll
          for (int q=0;q<4;++q)
            #pragma unroll
            for (int j=0;j<NNUC;++j) p[q][j] += __shfl_xor(p[q][j], s);
        if (lm==0){
          #pragma unroll
          for (int q=0;q<4;++q){
            const int row = row0 + w*16 + g*4 + q;
            #pragma unroll
            for (int j=0;j<NNUC;++j)
              a.nucp[((size_t)cgi*NROWS + row)*NNUC + j] = p[q][j];
          }
        }
      }
    }
    __threadfence();
    grid.sync();                               // gh, z, nuc partials visible
    if (!isA){
      if (tt<128) codes_s[tt] = a.nuc_idx[(size_t)(row0+tt)*LSEQ + t];
      s8b af[16];
      const s8b* grow = (const s8b*)(a.ghB + (size_t)(row0 + w*16 + lm)*HD);
      #pragma unroll
      for (int kc=0;kc<16;++kc) af[kc] = grow[kc*4 + g];
      __syncthreads();
      f4 acc[8];
      #pragma unroll
      for (int i=0;i<8;++i) acc[i]=f4zero();
      #pragma unroll
      for (int kc=0;kc<16;++kc){
        #pragma unroll
        for (int ot=0;ot<8;++ot){
          s8b b = ((const s8b*)&stage[kc][ot*512])[l];
          acc[ot] = MFMA16(af[kc], b, acc[ot]);
        }
      }
      #pragma unroll
      for (int ot=0;ot<8;++ot){
        const int col = colb + ot*16 + lm;
        #pragma unroll
        for (int q=0;q<4;++q){
          const int r = w*16 + g*4 + q;
          const size_t idx = (size_t)(row0+r)*HD + col;
          float pre = tanhf_fast(acc[ot][q] + a.wxbh[codes_s[r]*HD + col]);
          float zv = a.zF[idx];
          float hn = (1.f - zv)*a.hF[idx] + zv*pre;
          a.hF[idx] = hn;
          a.hB[idx] = (short)f2bf(hn);
        }
      }
      if (t > 0 && cgi == 0){
        for (int idx=tt; idx<128*NNUC; idx+=512){
          int rr = idx/NNUC, j = idx - rr*NNUC;
          int row = row0 + rr;
          float s2 = a.b_nuc[j];
          #pragma unroll
          for (int s4=0;s4<4;++s4) s2 += a.nucp[((size_t)s4*NROWS + row)*NNUC + j];
          a.out_nuc[((size_t)row*LSEQ + (t-1))*NNUC + j] = s2;
        }
      }
    }
    __threadfence();
    grid.sync();                               // h(t+1) visible
  }
}

// ---------------- fallback per-step kernels (round-11 verified) ----------------
__global__ __launch_bounds__(512) void zrnuc_k(
    int t, const int* __restrict__ nuc_idx,
    const short* __restrict__ fz, const short* __restrict__ fr, const short* __restrict__ fnuc,
    const short* __restrict__ hB, const float* __restrict__ hF,
    const float* __restrict__ wxbz, const float* __restrict__ wxbr,
    const float* __restrict__ latp, const float* __restrict__ w_nuc,
    float* __restrict__ zF, short* __restrict__ ghB, float* __restrict__ nucp)
{
  const int cg = blockIdx.y;
  const int mat = cg>>2;
  if (t==0 && mat==2) return;
  __shared__ __align__(16) short stage[16][4096];
  __shared__ int codes_s[128];
  const int tt = threadIdx.x, l = tt&63, w = tt>>6, lm = l&15, g = l>>4;
  const int row0 = blockIdx.x*128;
  const short* frag = (mat==0)?fz:((mat==1)?fr:fnuc);
  const int otb = (cg&3)*8;
  if (tt<128) codes_s[tt] = nuc_idx[(size_t)(row0+tt)*LSEQ + t];
  const short* gsrc = frag + ((size_t)(otb + w)*16)*512 + (size_t)l*8;
  #pragma unroll
  for (int kc=0;kc<8;++kc) dma16(gsrc + (size_t)kc*512, &stage[kc][w*512 + l*8]);
  s8b af[16];
  {
    const s8b* hrow = (const s8b*)(hB + (size_t)(row0 + w*16 + lm)*HD);
    #pragma unroll
    for (int kc=0;kc<16;++kc) af[kc] = hrow[kc*4 + g];
  }
  asm volatile("s_waitcnt vmcnt(0)" ::: "memory");
  __syncthreads();
  #pragma unroll
  for (int kc=8;kc<16;++kc) dma16(gsrc + (size_t)kc*512, &stage[kc][w*512 + l*8]);
  f4 acc[8];
  #pragma unroll
  for (int i=0;i<8;++i) acc[i]=f4zero();
  #pragma unroll
  for (int kc=0;kc<8;++kc){
    #pragma unroll
    for (int ot=0;ot<8;++ot){
      s8b b = ((const s8b*)&stage[kc][ot*512])[l];
      acc[ot] = MFMA16(af[kc], b, acc[ot]);
    }
  }
  asm volatile("s_waitcnt vmcnt(0)" ::: "memory");
  __syncthreads();
  #pragma unroll
  for (int kc=8;kc<16;++kc){
    #pragma unroll
    for (int ot=0;ot<8;++ot){
      s8b b = ((const s8b*)&stage[kc][ot*512])[l];
      acc[ot] = MFMA16(af[kc], b, acc[ot]);
    }
  }
  const int colb = (cg&3)*128;
  if (mat==0){
    #pragma unroll
    for (int ot=0;ot<8;++ot){
      const int col = colb + ot*16 + lm;
      #pragma unroll
      for (int q=0;q<4;++q){
        const int r = w*16 + g*4 + q;
        zF[(size_t)(row0+r)*HD + col] = sigf(acc[ot][q] + wxbz[codes_s[r]*HD + col]);
      }
    }
  } else if (mat==1){
    #pragma unroll
    for (int ot=0;ot<8;++ot){
      const int col = colb + ot*16 + lm;
      #pragma unroll
      for (int q=0;q<4;++q){
        const int r = w*16 + g*4 + q;
        float rv = sigf(acc[ot][q] + wxbr[codes_s[r]*HD + col]);
        ghB[(size_t)(row0+r)*HD + col] = (short)f2bf(rv * hF[(size_t)(row0+r)*HD + col]);
      }
    }
  } else {
    float p[4][NNUC];
    #pragma unroll
    for (int q=0;q<4;++q)
      #pragma unroll
      for (int j=0;j<NNUC;++j) p[q][j]=0.f;
    #pragma unroll
    for (int ot=0;ot<8;++ot){
      const int col = colb + ot*16 + lm;
      #pragma unroll
      for (int q=0;q<4;++q){
        const int r = w*16 + g*4 + q;
        float hid = fmaxf(acc[ot][q] + latp[(size_t)(row0+r)*HD + col], 0.f);
        #pragma unroll
        for (int j=0;j<NNUC;++j) p[q][j] = fmaf(hid, w_nuc[(size_t)j*HD + col], p[q][j]);
      }
    }
    #pragma unroll
    for (int s=1;s<16;s<<=1)
      #pragma unroll
      for (int q=0;q<4;++q)
        #pragma unroll
        for (int j=0;j<NNUC;++j) p[q][j] += __shfl_xor(p[q][j], s);
    if (lm==0){
      const int slab = cg&3;
      #pragma unroll
      for (int q=0;q<4;++q){
        const int row = row0 + w*16 + g*4 + q;
        #pragma unroll
        for (int j=0;j<NNUC;++j)
          nucp[((size_t)slab*NROWS + row)*NNUC + j] = p[q][j];
      }
    }
  }
}

__global__ __launch_bounds__(512) void cand_k(
    int t, const int* __restrict__ nuc_idx,
    const short* __restrict__ fh,
    const short* __restrict__ ghB,
    const float* __restrict__ wxbh,
    const float* __restrict__ zF, float* __restrict__ hF, short* __restrict__ hB,
    const float* __restrict__ nucp, const float* __restrict__ b_nuc,
    float* __restrict__ out_nuc)
{
  __shared__ __align__(16) short stage[16][4096];
  __shared__ int codes_s[64];
  const int tt = threadIdx.x, l = tt&63, w = tt>>6, lm = l&15, g = l>>4;
  const int row0 = blockIdx.x*64, cg = blockIdx.y;
  if (tt<64) codes_s[tt] = nuc_idx[(size_t)(row0+tt)*LSEQ + t];
  const int mt = w>>1, oth = w&1;
  const short* gsrc = fh + ((size_t)(cg*8 + w)*16)*512 + (size_t)l*8;
  #pragma unroll
  for (int kc=0;kc<8;++kc) dma16(gsrc + (size_t)kc*512, &stage[kc][w*512 + l*8]);
  s8b af[16];
  {
    const s8b* grow = (const s8b*)(ghB + (size_t)(row0 + mt*16 + lm)*HD);
    #pragma unroll
    for (int kc=0;kc<16;++kc) af[kc] = grow[kc*4 + g];
  }
  asm volatile("s_waitcnt vmcnt(0)" ::: "memory");
  __syncthreads();
  #pragma unroll
  for (int kc=8;kc<16;++kc) dma16(gsrc + (size_t)kc*512, &stage[kc][w*512 + l*8]);
  f4 acc[4];
  #pragma unroll
  for (int i=0;i<4;++i) acc[i]=f4zero();
  #pragma unroll
  for (int kc=0;kc<8;++kc){
    #pragma unroll
    for (int i=0;i<4;++i){
      s8b b = ((const s8b*)&stage[kc][(oth*4+i)*512])[l];
      acc[i] = MFMA16(af[kc], b, acc[i]);
    }
  }
  asm volatile("s_waitcnt vmcnt(0)" ::: "memory");
  __syncthreads();
  #pragma unroll
  for (int kc=8;kc<16;++kc){
    #pragma unroll
    for (int i=0;i<4;++i){
      s8b b = ((const s8b*)&stage[kc][(oth*4+i)*512])[l];
      acc[i] = MFMA16(af[kc], b, acc[i]);
    }
  }
  #pragma unroll
  for (int i=0;i<4;++i){
    const int col = cg*128 + (oth*4+i)*16 + lm;
    #pragma unroll
    for (int q=0;q<4;++q){
      const int r = mt*16 + g*4 + q;
      const size_t idx = (size_t)(row0+r)*HD + col;
      float pre = tanhf_fast(acc[i][q] + wxbh[codes_s[r]*HD + col]);
      float zv = zF[idx];
      float hn = (1.f - zv)*hF[idx] + zv*pre;
      hF[idx] = hn;
      hB[idx] = (short)f2bf(hn);
    }
  }
  if (t > 0 && cg == 0 && tt < 64*NNUC){
    int rr = tt/NNUC, j = tt - rr*NNUC;
    int row = row0 + rr;
    float s2 = b_nuc[j];
    #pragma unroll
    for (int s4=0;s4<4;++s4) s2 += nucp[((size_t)s4*NROWS + row)*NNUC + j];
    out_nuc[((size_t)row*LSEQ + (t-1))*NNUC + j] = s2;
  }
}

// ---------------- tail heads: nuc(l=63) + hpn on h(64) ----------------
__global__ __launch_bounds__(512) void heads_k(
    const short* __restrict__ fnuc, const short* __restrict__ fhpn,
    const short* __restrict__ hB,
    const float* __restrict__ latp, const float* __restrict__ w_nuc,
    const float* __restrict__ b_hpn_nl, const float* __restrict__ w_hpn,
    float* __restrict__ nucpH, float* __restrict__ hpnp)
{
  __shared__ __align__(16) short stage[16][4096];
  const int tt = threadIdx.x, l = tt&63, w = tt>>6, lm = l&15, g = l>>4;
  const int rt = blockIdx.x, row0 = rt*32, cg = blockIdx.y;
  const int mat = cg>>2;
  const short* frag = mat ? fhpn : fnuc;
  const int mt = w>>2, ntp = w&3;
  const short* gsrc = frag + ((size_t)((cg&3)*8 + w)*16)*512 + (size_t)l*8;
  #pragma unroll
  for (int kc=0;kc<8;++kc) dma16(gsrc + (size_t)kc*512, &stage[kc][w*512 + l*8]);
  s8b af[16];
  {
    const s8b* hrow = (const s8b*)(hB + (size_t)(row0 + mt*16 + lm)*HD);
    #pragma unroll
    for (int kc=0;kc<16;++kc) af[kc] = hrow[kc*4 + g];
  }
  asm volatile("s_waitcnt vmcnt(0)" ::: "memory");
  __syncthreads();
  #pragma unroll
  for (int kc=8;kc<16;++kc) dma16(gsrc + (size_t)kc*512, &stage[kc][w*512 + l*8]);
  f4 acc[2]; acc[0]=f4zero(); acc[1]=f4zero();
  #pragma unroll
  for (int kc=0;kc<8;++kc){
    #pragma unroll
    for (int i2=0;i2<2;++i2){
      s8b b = ((const s8b*)&stage[kc][(ntp*2+i2)*512])[l];
      acc[i2] = MFMA16(af[kc], b, acc[i2]);
    }
  }
  asm volatile("s_waitcnt vmcnt(0)" ::: "memory");
  __syncthreads();
  #pragma unroll
  for (int kc=8;kc<16;++kc){
    #pragma unroll
    for (int i2=0;i2<2;++i2){
      s8b b = ((const s8b*)&stage[kc][(ntp*2+i2)*512])[l];
      acc[i2] = MFMA16(af[kc], b, acc[i2]);
    }
  }
  const int slab = (cg&3)*4 + ntp;
  if (mat==0){
    float p[4][NNUC];
    #pragma unroll
    for (int q=0;q<4;++q)
      #pragma unroll
      for (int j=0;j<NNUC;++j) p[q][j]=0.f;
    #pragma unroll
    for (int i2=0;i2<2;++i2){
      const int col = (cg&3)*128 + (ntp*2+i2)*16 + lm;
      #pragma unroll
      for (int q=0;q<4;++q){
        const int r = mt*16 + g*4 + q;
        float hid = fmaxf(acc[i2][q] + latp[(size_t)(row0+r)*HD + col], 0.f);
        #pragma unroll
        for (int j=0;j<NNUC;++j) p[q][j] = fmaf(hid, w_nuc[(size_t)j*HD + col], p[q][j]);
      }
    }
    #pragma unroll
    for (int s=1;s<16;s<<=1)
      #pragma unroll
      for (int q=0;q<4;++q)
        #pragma unroll
        for (int j=0;j<NNUC;++j) p[q][j] += __shfl_xor(p[q][j], s);
    if (lm==0){
      #pragma unroll
      for (int q=0;q<4;++q){
        const int row = row0 + mt*16 + g*4 + q;
        #pragma unroll
        for (int j=0;j<NNUC;++j)
          nucpH[((size_t)slab*NROWS + row)*NNUC + j] = p[q][j];
      }
    }
  } else {
    float p[4][NHPN];
    #pragma unroll
    for (int q=0;q<4;++q)
      #pragma unroll
      for (int j=0;j<NHPN;++j) p[q][j]=0.f;
    #pragma unroll
    for (int i2=0;i2<2;++i2){
      const int col = (cg&3)*128 + (ntp*2+i2)*16 + lm;
      float bnl = b_hpn_nl[col];
      #pragma unroll
      for (int q=0;q<4;++q){
        float hid = fmaxf(acc[i2][q] + bnl, 0.f);
        #pragma unroll
        for (int j=0;j<NHPN;++j) p[q][j] = fmaf(hid, w_hpn[(size_t)j*HD + col], p[q][j]);
      }
    }
    #pragma unroll
    for (int s=1;s<16;s<<=1)
      #pragma unroll
      for (int q=0;q<4;++q)
        #pragma unroll
        for (int j=0;j<NHPN;++j) p[q][j] += __shfl_xor(p[q][j], s);
    if (lm==0){
      #pragma unroll
      for (int q=0;q<4;++q){
        const int row = row0 + mt*16 + g*4 + q;
        #pragma unroll
        for (int j=0;j<NHPN;++j)
          hpnp[((size_t)slab*NROWS + row)*NHPN + j] = p[q][j];
      }
    }
  }
}

__global__ void final_red_k(const float* __restrict__ nucpH, const float* __restrict__ hpnp,
    const float* __restrict__ topo_p,
    const float* __restrict__ b_nuc, const float* __restrict__ b_hpn, const float* __restrict__ b_topo,
    const float* __restrict__ hF,
    float* __restrict__ out_newh, float* __restrict__ out_hpn, float* __restrict__ out_nuc,
    float* __restrict__ out_stop)
{
  int gid = blockIdx.x*256 + threadIdx.x;   // grid 128x256 = 32768
  if (gid < NROWS*NNUC){
    int n = gid/NNUC, j = gid - n*NNUC;
    float s = b_nuc[j];
    #pragma unroll
    for (int s8=0;s8<16;++s8) s += nucpH[((size_t)s8*NROWS + n)*NNUC + j];
    out_nuc[((size_t)n*LSEQ + 63)*NNUC + j] = s;
  } else if (gid < NROWS*NNUC + NROWS*NHPN){
    int g2 = gid - NROWS*NNUC;
    int n = g2/NHPN, j = g2 - n*NHPN;
    float s = b_hpn[j];
    #pragma unroll
    for (int s8=0;s8<16;++s8) s += hpnp[((size_t)s8*NROWS + n)*NHPN + j];
    out_hpn[(size_t)n*NHPN + j] = s;
  } else if (gid < NROWS*NNUC + NROWS*NHPN + NROWS){
    int n = gid - (NROWS*NNUC + NROWS*NHPN);
    float s = b_topo[0];
    #pragma unroll
    for (int s16=0;s16<16;++s16) s += topo_p[(size_t)s16*NROWS + n];
    out_stop[n] = s;
  }
  const float4* src = (const float4*)hF;
  float4* dst = (float4*)out_newh;
  for (int i = gid; i < NROWS*HD/4; i += 32768) dst[i] = src[i];
}

// ---------------- host ----------------
extern "C" void kernel_launch(void* const* d_in, const int* in_sizes, int n_in,
                              void* d_out, int out_size, void* d_ws, size_t ws_size,
                              hipStream_t stream_){
  (void)in_sizes; (void)n_in; (void)out_size; (void)ws_size;
  const int*   hpn_idx      = (const int*)d_in[0];
  const int*   nuc_idx      = (const int*)d_in[1];
  const float* h_nei        = (const float*)d_in[2];
  const float* graph_latent = (const float*)d_in[3];
  const float* Wz_mp=(const float*)d_in[4];  const float* bz_mp=(const float*)d_in[5];
  const float* Wr_mp=(const float*)d_in[6];  const float* br_mp=(const float*)d_in[7];
  const float* Ur_mp=(const float*)d_in[8];
  const float* Wh_mp=(const float*)d_in[9];  const float* bh_mp=(const float*)d_in[10];
  const float* Wz_nuc=(const float*)d_in[11]; const float* bz_nuc=(const float*)d_in[12];
  const float* Wr_nuc=(const float*)d_in[13]; const float* br_nuc=(const float*)d_in[14];
  const float* Wh_nuc=(const float*)d_in[15]; const float* bh_nuc=(const float*)d_in[16];
  const float* W_hpn_nl=(const float*)d_in[17]; const float* b_hpn_nl=(const float*)d_in[18];
  const float* W_hpn=(const float*)d_in[19];  const float* b_hpn=(const float*)d_in[20];
  const float* W_nuc_nl=(const float*)d_in[21]; const float* b_nuc_nl=(const float*)d_in[22];
  const float* W_nuc=(const float*)d_in[23];  const float* b_nuc=(const float*)d_in[24];
  const float* W_topo_nl=(const float*)d_in[25]; const float* b_topo_nl=(const float*)d_in[26];
  const float* W_topo=(const float*)d_in[27]; const float* b_topo=(const float*)d_in[28];

  float* ws = (float*)d_ws;
  size_t off = 0;
  auto take = [&](size_t nfl){ float* p = ws + off; off += nfl; return p; };
  float* wt_nl_lat = take((size_t)LATD*HD);
  short* fz    = (short*)take((size_t)HD*HD/2);
  short* fr    = (short*)take((size_t)HD*HD/2);
  short* fh    = (short*)take((size_t)HD*HD/2);
  short* fnuc  = (short*)take((size_t)HD*HD/2);
  short* fhpn  = (short*)take((size_t)HD*HD/2);
  short* fWzh  = (short*)take((size_t)HD*HD/2);
  short* fUr   = (short*)take((size_t)HD*HD/2);
  short* fWhh  = (short*)take((size_t)HD*HD/2);
  short* fWtopo= (short*)take((size_t)HD*HD/2);
  float* wxbz = take((size_t)NNUC*HD);
  float* wxbr = take((size_t)NNUC*HD);
  float* wxbh = take((size_t)NNUC*HD);
  float* wxbz_mp = take((size_t)NHPN*HD);
  float* wxbr_mp = take((size_t)NHPN*HD);
  float* wxbh_mp = take((size_t)NHPN*HD);
  float* latp = take((size_t)NROWS*HD);
  float* hF   = take((size_t)NROWS*HD);
  short* hB   = (short*)take((size_t)NROWS*HD/2);
  short* ghB  = (short*)take((size_t)NROWS*HD/2);
  float* zF   = take((size_t)NROWS*HD);
  float* sumhF = take((size_t)NROWS*HD);
  short* sumhB = (short*)take((size_t)NROWS*HD/2);
  short* sgB   = (short*)take((size_t)NROWS*HD/2);
  short* hnB   = (short*)take((size_t)NROWS*KNEI*HD/2);
  float* nucp = take((size_t)4*NROWS*NNUC);
  float* nucpH= take((size_t)16*NROWS*NNUC);
  float* hpnp = take((size_t)16*NROWS*NHPN);
  float* topo_p = take((size_t)16*NROWS);

  float* out       = (float*)d_out;
  float* out_newh  = out;
  float* out_hpn   = out + (size_t)NROWS*HD;
  float* out_nuc   = out_hpn + (size_t)NROWS*NHPN;
  float* out_stop  = out_nuc + (size_t)NROWS*LSEQ*NNUC;

  transpose_w<<<(LATD*HD+255)/256, 256, 0, stream_>>>(W_nuc_nl, wt_nl_lat, HD+LATD, HD, LATD);

  const int FB = (HD*HD+255)/256;
  fragprep_k<<<FB,256,0,stream_>>>(Wz_nuc,   fz,    HD+NNUC, NNUC);
  fragprep_k<<<FB,256,0,stream_>>>(Wr_nuc,   fr,    HD+NNUC, NNUC);
  fragprep_k<<<FB,256,0,stream_>>>(Wh_nuc,   fh,    HD+NNUC, NNUC);
  fragprep_k<<<FB,256,0,stream_>>>(W_nuc_nl, fnuc,  HD+LATD, 0);
  fragprep_k<<<FB,256,0,stream_>>>(W_hpn_nl, fhpn,  HD,      0);
  fragprep_k<<<FB,256,0,stream_>>>(Wz_mp,    fWzh,  HD+NHPN, NHPN);
  fragprep_k<<<FB,256,0,stream_>>>(Ur_mp,    fUr,   HD,      0);
  fragprep_k<<<FB,256,0,stream_>>>(Wh_mp,    fWhh,  HD+NHPN, NHPN);
  fragprep_k<<<FB,256,0,stream_>>>(W_topo_nl,fWtopo,HD,      0);

  const int WB = (NNUC*HD+255)/256;
  wxbprep2_k<<<WB,256,0,stream_>>>(Wz_nuc, bz_nuc, wxbz, HD+NNUC, NNUC);
  wxbprep2_k<<<WB,256,0,stream_>>>(Wr_nuc, br_nuc, wxbr, HD+NNUC, NNUC);
  wxbprep2_k<<<WB,256,0,stream_>>>(Wh_nuc, bh_nuc, wxbh, HD+NNUC, NNUC);
  const int WB2 = (NHPN*HD+255)/256;
  wxbprep2_k<<<WB2,256,0,stream_>>>(Wz_mp, bz_mp, wxbz_mp, HD+NHPN, NHPN);
  wxbprep2_k<<<WB2,256,0,stream_>>>(Wr_mp, br_mp, wxbr_mp, NHPN,    NHPN);
  wxbprep2_k<<<WB2,256,0,stream_>>>(Wh_mp, bh_mp, wxbh_mp, HD+NHPN, NHPN);

  latp_k<<<NROWS/16, 512, 0, stream_>>>(graph_latent, wt_nl_lat, b_nuc_nl, latp);

  // ---- GraphGRU via MFMA ----
  sumcast_k<<<512, 512, 0, stream_>>>(h_nei, sumhF, sumhB, hnB);
  ggru_gemm_k<<<dim3(64,4), 512, 0, stream_>>>(
      0, fWzh, sumhB, hpn_idx, wxbz_mp, nullptr, nullptr, nullptr,
      zF, nullptr, nullptr, nullptr);
  ggru_r_k<<<dim3(128,4), 512, 0, stream_>>>(fUr, hnB, hpn_idx, wxbr_mp, sgB);
  ggru_gemm_k<<<dim3(64,4), 512, 0, stream_>>>(
      1, fWhh, sgB, hpn_idx, wxbh_mp, sumhF, zF, nullptr,
      nullptr, hF, hB, nullptr);
  ggru_gemm_k<<<dim3(64,4), 512, 0, stream_>>>(
      2, fWtopo, hB, hpn_idx, b_topo_nl, nullptr, nullptr, W_topo,
      nullptr, nullptr, nullptr, topo_p);

  // ---- scan: persistent cooperative kernel (fallback: per-step loop) ----
  ScanArgs sargs;
  sargs.nuc_idx = nuc_idx;
  sargs.fz = fz; sargs.fr = fr; sargs.fnuc = fnuc; sargs.fh = fh;
  sargs.hB = hB; sargs.hF = hF;
  sargs.wxbz = wxbz; sargs.wxbr = wxbr; sargs.wxbh = wxbh;
  sargs.latp = latp; sargs.w_nuc = W_nuc; sargs.b_nuc = b_nuc;
  sargs.zF = zF; sargs.ghB = ghB; sargs.nucp = nucp; sargs.out_nuc = out_nuc;
  void* kargs[] = { (void*)&sargs };
  hipError_t cerr = hipLaunchCooperativeKernel(
      (const void*)scan_coop_k, dim3(256), dim3(512), kargs, 0, stream_);
  if (cerr != hipSuccess){
    for (int t = 0; t < LSEQ; ++t){
      zrnuc_k<<<dim3(16,12), 512, 0, stream_>>>(
          t, nuc_idx, fz, fr, fnuc, hB, hF,
          wxbz, wxbr, latp, W_nuc, zF, ghB, nucp);
      cand_k<<<dim3(32,4), 512, 0, stream_>>>(
          t, nuc_idx, fh, ghB, wxbh, zF, hF, hB,
          nucp, b_nuc, out_nuc);
    }
  }

  heads_k<<<dim3(64,8), 512, 0, stream_>>>(
      fnuc, fhpn, hB, latp, W_nuc, b_hpn_nl, W_hpn, nucpH, hpnp);
  final_red_k<<<128, 256, 0, stream_>>>(
      nucpH, hpnp, topo_p, b_nuc, b_hpn, b_topo, hF,
      out_newh, out_hpn, out_nuc, out_stop);
}

// Round 13
// 1826.488 us; speedup vs baseline: 7.1545x; 7.1545x over previous
//
#include <hip/hip_runtime.h>
#include <math.h>

#define NROWS 2048
#define KNEI  8
#define LSEQ  64
#define HD    512
#define HD4   128
#define LATD  128
#define NHPN  4
#define NNUC  5

typedef __attribute__((ext_vector_type(8))) short s8b;   // 8 bf16 (16B)
typedef __attribute__((ext_vector_type(4))) short s4b;   // 4 bf16 (8B)
typedef __attribute__((ext_vector_type(4))) float f4;    // MFMA acc

#define MFMA16(a,b,c) __builtin_amdgcn_mfma_f32_16x16x32_bf16(a,b,c,0,0,0)

__device__ __forceinline__ f4 f4zero(){ f4 z; z[0]=0.f; z[1]=0.f; z[2]=0.f; z[3]=0.f; return z; }
__device__ __forceinline__ float sigf(float x){ return __fdividef(1.0f, 1.0f + __expf(-x)); }
__device__ __forceinline__ float tanhf_fast(float x){
  float e = __expf(-2.0f*fabsf(x));
  float t = __fdividef(1.0f - e, 1.0f + e);
  return x >= 0.f ? t : -t;
}
__device__ __forceinline__ unsigned short f2bf(float x){
  union{float f; unsigned u;} v; v.f = x;
  unsigned r = (v.u + 0x7FFFu + ((v.u>>16)&1u)) >> 16;
  return (unsigned short)r;
}
__device__ __forceinline__ float bf2f(unsigned short u){
  union{unsigned x; float f;} v; v.x = ((unsigned)u)<<16; return v.f;
}
__device__ __forceinline__ void add4(float4& a, float4 b){ a.x+=b.x; a.y+=b.y; a.z+=b.z; a.w+=b.w; }

__device__ __forceinline__ void dma16(const short* g, const short* l){
  __builtin_amdgcn_global_load_lds(
      (const __attribute__((address_space(1))) void*)(unsigned long long)g,
      (__attribute__((address_space(3))) void*)(unsigned long long)l,
      16, 0, 0);
}

// ---------------- prep kernels ----------------

__global__ void transpose_w(const float* __restrict__ src, float* __restrict__ dst,
                            int src_cols, int col_off, int nh){
  int idx = blockIdx.x*256 + threadIdx.x;
  if (idx >= nh*HD) return;
  int h = idx / HD, o = idx - h*HD;
  dst[idx] = src[o*src_cols + col_off + h];
}

// fused 9-matrix B-frag prep: dst[m][tile*512 + l*8 + j] = W[m][row][k]
struct Frag9 {
  const float* W[9];
  short* dst[9];
  int sc[9];
  int co[9];
};
__global__ void fragprep9_k(Frag9 a){
  int bid = blockIdx.x;               // 9*1024 blocks
  int m = bid >> 10;
  int idx = ((bid & 1023) << 8) + threadIdx.x;
  int j = idx&7, l = (idx>>3)&63, tile = idx>>9;
  int kc = tile&15, ot = tile>>4;
  int row = ot*16 + (l&15), k = kc*32 + (l>>4)*8 + j;
  a.dst[m][idx] = (short)f2bf(a.W[m][(size_t)row*a.sc[m] + a.co[m] + k]);
}

// fused 6-table wxb prep: dst[m][c*HD + n] = W[m][n*sc+c] + b[m][n]
struct Wxb6 {
  const float* W[6];
  const float* b[6];
  float* dst[6];
  int sc[6];
  int nc[6];
};
__global__ void wxb6_k(Wxb6 a){
  int m = blockIdx.x / 10;            // 60 blocks (10 per table)
  int idx = (blockIdx.x % 10)*256 + threadIdx.x;
  if (idx >= a.nc[m]*HD) return;
  int c = idx/HD, n = idx - c*HD;
  a.dst[m][idx] = a.W[m][(size_t)n*a.sc[m] + c] + a.b[m][n];
}

// latp[n][o] = b_nl[o] + sum_q gl[n][q]*wtlat[q*HD+o]
__global__ __launch_bounds__(512) void latp_k(const float* __restrict__ gl, const float* __restrict__ wtlat,
                     const float* __restrict__ bnl, float* __restrict__ latp){
  __shared__ float gls[16][LATD];
  int b = blockIdx.x, t = threadIdx.x;
  for (int i=t;i<16*LATD;i+=512) gls[i/LATD][i%LATD] = gl[(size_t)(b*16)*LATD + i];
  __syncthreads();
  float acc[16];
  float bv = bnl[t];
  #pragma unroll
  for (int r=0;r<16;++r) acc[r]=bv;
  for (int q=0;q<LATD;++q){
    float wv = wtlat[(size_t)q*HD + t];
    #pragma unroll
    for (int r=0;r<16;++r) acc[r] = fmaf(gls[r][q], wv, acc[r]);
  }
  #pragma unroll
  for (int r=0;r<16;++r) latp[(size_t)(b*16+r)*HD + t] = acc[r];
}

// sumh = h_nei.sum(k): fp32 + bf16 copies; also bf16 copy of full h_nei (hnB).
__global__ void sumcast_k(const float* __restrict__ h_nei,
                          float* __restrict__ sumhF, short* __restrict__ sumhB,
                          short* __restrict__ hnB){
  int idx = blockIdx.x*512 + threadIdx.x;
  int n = idx >> 7, c4 = idx & 127;
  const float4* hn4 = (const float4*)h_nei;
  size_t base = (size_t)n*KNEI*HD4 + c4;
  float4 s = make_float4(0.f,0.f,0.f,0.f);
  #pragma unroll
  for (int k=0;k<KNEI;++k){
    float4 v = hn4[base + (size_t)k*HD4];
    add4(s, v);
    s4b pb;
    pb[0]=(short)f2bf(v.x); pb[1]=(short)f2bf(v.y); pb[2]=(short)f2bf(v.z); pb[3]=(short)f2bf(v.w);
    ((s4b*)hnB)[(size_t)(n*KNEI + k)*HD4 + c4] = pb;
  }
  ((float4*)sumhF)[(size_t)n*HD4 + c4] = s;
  s4b p;
  p[0]=(short)f2bf(s.x); p[1]=(short)f2bf(s.y); p[2]=(short)f2bf(s.z); p[3]=(short)f2bf(s.w);
  ((s4b*)sumhB)[(size_t)n*HD4 + c4] = p;
}

// ---------------- GraphGRU MFMA GEMMs ----------------
__global__ __launch_bounds__(512) void ggru_gemm_k(
    int mode,
    const short* __restrict__ frag,
    const short* __restrict__ A,
    const int* __restrict__ hpn_idx,
    const float* __restrict__ bias_tab,
    const float* __restrict__ sumhF, const float* __restrict__ zF_in,
    const float* __restrict__ w_topo,
    float* __restrict__ zF_out,
    float* __restrict__ hF, short* __restrict__ hB,
    float* __restrict__ topo_p)
{
  __shared__ __align__(16) short stage[16][4096];
  __shared__ int codes_s[32];
  const int tt = threadIdx.x, l = tt&63, w = tt>>6, lm = l&15, g = l>>4;
  const int rt = blockIdx.x, row0 = rt*32, cg = blockIdx.y;
  if (tt<32) codes_s[tt] = hpn_idx[row0+tt];
  const int mt = w>>2, ntp = w&3;
  const short* gsrc = frag + ((size_t)(cg*8 + w)*16)*512 + (size_t)l*8;
  #pragma unroll
  for (int kc=0;kc<8;++kc) dma16(gsrc + (size_t)kc*512, &stage[kc][w*512 + l*8]);
  s8b af[16];
  {
    const s8b* arow = (const s8b*)(A + (size_t)(row0 + mt*16 + lm)*HD);
    #pragma unroll
    for (int kc=0;kc<16;++kc) af[kc] = arow[kc*4 + g];
  }
  asm volatile("s_waitcnt vmcnt(0)" ::: "memory");
  __syncthreads();
  #pragma unroll
  for (int kc=8;kc<16;++kc) dma16(gsrc + (size_t)kc*512, &stage[kc][w*512 + l*8]);
  f4 acc[2]; acc[0]=f4zero(); acc[1]=f4zero();
  #pragma unroll
  for (int kc=0;kc<8;++kc){
    #pragma unroll
    for (int i2=0;i2<2;++i2){
      s8b b = ((const s8b*)&stage[kc][(ntp*2+i2)*512])[l];
      acc[i2] = MFMA16(af[kc], b, acc[i2]);
    }
  }
  asm volatile("s_waitcnt vmcnt(0)" ::: "memory");
  __syncthreads();
  #pragma unroll
  for (int kc=8;kc<16;++kc){
    #pragma unroll
    for (int i2=0;i2<2;++i2){
      s8b b = ((const s8b*)&stage[kc][(ntp*2+i2)*512])[l];
      acc[i2] = MFMA16(af[kc], b, acc[i2]);
    }
  }
  if (mode==0){
    #pragma unroll
    for (int i2=0;i2<2;++i2){
      const int col = cg*128 + (ntp*2+i2)*16 + lm;
      #pragma unroll
      for (int q=0;q<4;++q){
        const int r = mt*16 + g*4 + q;
        zF_out[(size_t)(row0+r)*HD + col] = sigf(acc[i2][q] + bias_tab[codes_s[r]*HD + col]);
      }
    }
  } else if (mode==1){
    #pragma unroll
    for (int i2=0;i2<2;++i2){
      const int col = cg*128 + (ntp*2+i2)*16 + lm;
      #pragma unroll
      for (int q=0;q<4;++q){
        const int r = mt*16 + g*4 + q;
        const size_t idx = (size_t)(row0+r)*HD + col;
        float pre = tanhf_fast(acc[i2][q] + bias_tab[codes_s[r]*HD + col]);
        float zv = zF_in[idx];
        float m = (1.f - zv)*sumhF[idx] + zv*pre;
        hF[idx] = m;
        hB[idx] = (short)f2bf(m);
      }
    }
  } else {
    float p[4];
    #pragma unroll
    for (int q=0;q<4;++q) p[q]=0.f;
    #pragma unroll
    for (int i2=0;i2<2;++i2){
      const int col = cg*128 + (ntp*2+i2)*16 + lm;
      float wv = w_topo[col];
      float bnl = bias_tab[col];
      #pragma unroll
      for (int q=0;q<4;++q){
        float hid = fmaxf(acc[i2][q] + bnl, 0.f);
        p[q] = fmaf(hid, wv, p[q]);
      }
    }
    #pragma unroll
    for (int s=1;s<16;s<<=1)
      #pragma unroll
      for (int q=0;q<4;++q) p[q] += __shfl_xor(p[q], s);
    if (lm==0){
      #pragma unroll
      for (int q=0;q<4;++q)
        topo_p[(size_t)(cg*4+ntp)*NROWS + row0 + mt*16 + g*4 + q] = p[q];
    }
  }
}

// r gate: [16384,512] x Ur^T with in-register k-reduction -> sum_gated bf16.
__global__ __launch_bounds__(512) void ggru_r_k(
    const short* __restrict__ fUr,
    const short* __restrict__ hnB,
    const int* __restrict__ hpn_idx,
    const float* __restrict__ wxbr_mp,
    short* __restrict__ sgB)
{
  __shared__ __align__(16) short stage[16][4096];
  __shared__ int codes_s[16];
  const int tt = threadIdx.x, l = tt&63, w = tt>>6, lm = l&15, g = l>>4;
  const int row0 = blockIdx.x*128, cg = blockIdx.y;
  if (tt<16) codes_s[tt] = hpn_idx[(row0>>3) + tt];
  const short* gsrc = fUr + ((size_t)(cg*8 + w)*16)*512 + (size_t)l*8;
  #pragma unroll
  for (int kc=0;kc<8;++kc) dma16(gsrc + (size_t)kc*512, &stage[kc][w*512 + l*8]);
  s8b af[16];
  {
    const s8b* arow = (const s8b*)(hnB + (size_t)(row0 + w*16 + lm)*HD);
    #pragma unroll
    for (int kc=0;kc<16;++kc) af[kc] = arow[kc*4 + g];
  }
  asm volatile("s_waitcnt vmcnt(0)" ::: "memory");
  __syncthreads();
  #pragma unroll
  for (int kc=8;kc<16;++kc) dma16(gsrc + (size_t)kc*512, &stage[kc][w*512 + l*8]);
  f4 acc[8];
  #pragma unroll
  for (int i=0;i<8;++i) acc[i]=f4zero();
  #pragma unroll
  for (int kc=0;kc<8;++kc){
    #pragma unroll
    for (int ot=0;ot<8;++ot){
      s8b b = ((const s8b*)&stage[kc][ot*512])[l];
      acc[ot] = MFMA16(af[kc], b, acc[ot]);
    }
  }
  asm volatile("s_waitcnt vmcnt(0)" ::: "memory");
  __syncthreads();
  #pragma unroll
  for (int kc=8;kc<16;++kc){
    #pragma unroll
    for (int ot=0;ot<8;++ot){
      s8b b = ((const s8b*)&stage[kc][ot*512])[l];
      acc[ot] = MFMA16(af[kc], b, acc[ot]);
    }
  }
  const int nloc = w*2 + (g>>1);
  const int code = codes_s[nloc];
  #pragma unroll
  for (int ot=0;ot<8;++ot){
    const int col = cg*128 + ot*16 + lm;
    float part = 0.f;
    #pragma unroll
    for (int q=0;q<4;++q){
      const int lr = w*16 + g*4 + q;
      float rv = sigf(acc[ot][q] + wxbr_mp[code*HD + col]);
      part += rv * bf2f((unsigned short)hnB[(size_t)(row0+lr)*HD + col]);
    }
    part += __shfl_xor(part, 16);
    if ((g&1)==0){
      const int node = (row0>>3) + nloc;
      sgB[(size_t)node*HD + col] = (short)f2bf(part);
    }
  }
}

// ---------------- scan step kernel A: z, r, nuc GEMMs on h(t) ----------------
__global__ __launch_bounds__(512) void zrnuc_k(
    int t, const int* __restrict__ nuc_idx,
    const short* __restrict__ fz, const short* __restrict__ fr, const short* __restrict__ fnuc,
    const short* __restrict__ hB, const float* __restrict__ hF,
    const float* __restrict__ wxbz, const float* __restrict__ wxbr,
    const float* __restrict__ latp, const float* __restrict__ w_nuc,
    float* __restrict__ zF, short* __restrict__ ghB, float* __restrict__ nucp)
{
  const int cg = blockIdx.y;
  const int mat = cg>>2;
  if (t==0 && mat==2) return;
  __shared__ __align__(16) short stage[16][4096];
  __shared__ int codes_s[128];
  const int tt = threadIdx.x, l = tt&63, w = tt>>6, lm = l&15, g = l>>4;
  const int row0 = blockIdx.x*128;
  const short* frag = (mat==0)?fz:((mat==1)?fr:fnuc);
  const int otb = (cg&3)*8;
  if (tt<128) codes_s[tt] = nuc_idx[(size_t)(row0+tt)*LSEQ + t];
  const short* gsrc = frag + ((size_t)(otb + w)*16)*512 + (size_t)l*8;
  #pragma unroll
  for (int kc=0;kc<8;++kc) dma16(gsrc + (size_t)kc*512, &stage[kc][w*512 + l*8]);
  s8b af[16];
  {
    const s8b* hrow = (const s8b*)(hB + (size_t)(row0 + w*16 + lm)*HD);
    #pragma unroll
    for (int kc=0;kc<16;++kc) af[kc] = hrow[kc*4 + g];
  }
  asm volatile("s_waitcnt vmcnt(0)" ::: "memory");
  __syncthreads();
  #pragma unroll
  for (int kc=8;kc<16;++kc) dma16(gsrc + (size_t)kc*512, &stage[kc][w*512 + l*8]);
  f4 acc[8];
  #pragma unroll
  for (int i=0;i<8;++i) acc[i]=f4zero();
  #pragma unroll
  for (int kc=0;kc<8;++kc){
    #pragma unroll
    for (int ot=0;ot<8;++ot){
      s8b b = ((const s8b*)&stage[kc][ot*512])[l];
      acc[ot] = MFMA16(af[kc], b, acc[ot]);
    }
  }
  asm volatile("s_waitcnt vmcnt(0)" ::: "memory");
  __syncthreads();
  #pragma unroll
  for (int kc=8;kc<16;++kc){
    #pragma unroll
    for (int ot=0;ot<8;++ot){
      s8b b = ((const s8b*)&stage[kc][ot*512])[l];
      acc[ot] = MFMA16(af[kc], b, acc[ot]);
    }
  }
  const int colb = (cg&3)*128;
  if (mat==0){
    #pragma unroll
    for (int ot=0;ot<8;++ot){
      const int col = colb + ot*16 + lm;
      #pragma unroll
      for (int q=0;q<4;++q){
        const int r = w*16 + g*4 + q;
        zF[(size_t)(row0+r)*HD + col] = sigf(acc[ot][q] + wxbz[codes_s[r]*HD + col]);
      }
    }
  } else if (mat==1){
    #pragma unroll
    for (int ot=0;ot<8;++ot){
      const int col = colb + ot*16 + lm;
      #pragma unroll
      for (int q=0;q<4;++q){
        const int r = w*16 + g*4 + q;
        float rv = sigf(acc[ot][q] + wxbr[codes_s[r]*HD + col]);
        ghB[(size_t)(row0+r)*HD + col] = (short)f2bf(rv * hF[(size_t)(row0+r)*HD + col]);
      }
    }
  } else {
    float p[4][NNUC];
    #pragma unroll
    for (int q=0;q<4;++q)
      #pragma unroll
      for (int j=0;j<NNUC;++j) p[q][j]=0.f;
    #pragma unroll
    for (int ot=0;ot<8;++ot){
      const int col = colb + ot*16 + lm;
      #pragma unroll
      for (int q=0;q<4;++q){
        const int r = w*16 + g*4 + q;
        float hid = fmaxf(acc[ot][q] + latp[(size_t)(row0+r)*HD + col], 0.f);
        #pragma unroll
        for (int j=0;j<NNUC;++j) p[q][j] = fmaf(hid, w_nuc[(size_t)j*HD + col], p[q][j]);
      }
    }
    #pragma unroll
    for (int s=1;s<16;s<<=1)
      #pragma unroll
      for (int q=0;q<4;++q)
        #pragma unroll
        for (int j=0;j<NNUC;++j) p[q][j] += __shfl_xor(p[q][j], s);
    if (lm==0){
      const int slab = cg&3;
      #pragma unroll
      for (int q=0;q<4;++q){
        const int row = row0 + w*16 + g*4 + q;
        #pragma unroll
        for (int j=0;j<NNUC;++j)
          nucp[((size_t)slab*NROWS + row)*NNUC + j] = p[q][j];
      }
    }
  }
}

// ---------------- scan step kernel B: candidate GEMM + h update ----------------
__global__ __launch_bounds__(512) void cand_k(
    int t, const int* __restrict__ nuc_idx,
    const short* __restrict__ fh,
    const short* __restrict__ ghB,
    const float* __restrict__ wxbh,
    const float* __restrict__ zF, float* __restrict__ hF, short* __restrict__ hB,
    const float* __restrict__ nucp, const float* __restrict__ b_nuc,
    float* __restrict__ out_nuc)
{
  __shared__ __align__(16) short stage[16][4096];
  __shared__ int codes_s[64];
  const int tt = threadIdx.x, l = tt&63, w = tt>>6, lm = l&15, g = l>>4;
  const int row0 = blockIdx.x*64, cg = blockIdx.y;
  if (tt<64) codes_s[tt] = nuc_idx[(size_t)(row0+tt)*LSEQ + t];
  const int mt = w>>1, oth = w&1;
  const short* gsrc = fh + ((size_t)(cg*8 + w)*16)*512 + (size_t)l*8;
  #pragma unroll
  for (int kc=0;kc<8;++kc) dma16(gsrc + (size_t)kc*512, &stage[kc][w*512 + l*8]);
  s8b af[16];
  {
    const s8b* grow = (const s8b*)(ghB + (size_t)(row0 + mt*16 + lm)*HD);
    #pragma unroll
    for (int kc=0;kc<16;++kc) af[kc] = grow[kc*4 + g];
  }
  asm volatile("s_waitcnt vmcnt(0)" ::: "memory");
  __syncthreads();
  #pragma unroll
  for (int kc=8;kc<16;++kc) dma16(gsrc + (size_t)kc*512, &stage[kc][w*512 + l*8]);
  f4 acc[4];
  #pragma unroll
  for (int i=0;i<4;++i) acc[i]=f4zero();
  #pragma unroll
  for (int kc=0;kc<8;++kc){
    #pragma unroll
    for (int i=0;i<4;++i){
      s8b b = ((const s8b*)&stage[kc][(oth*4+i)*512])[l];
      acc[i] = MFMA16(af[kc], b, acc[i]);
    }
  }
  asm volatile("s_waitcnt vmcnt(0)" ::: "memory");
  __syncthreads();
  #pragma unroll
  for (int kc=8;kc<16;++kc){
    #pragma unroll
    for (int i=0;i<4;++i){
      s8b b = ((const s8b*)&stage[kc][(oth*4+i)*512])[l];
      acc[i] = MFMA16(af[kc], b, acc[i]);
    }
  }
  #pragma unroll
  for (int i=0;i<4;++i){
    const int col = cg*128 + (oth*4+i)*16 + lm;
    #pragma unroll
    for (int q=0;q<4;++q){
      const int r = mt*16 + g*4 + q;
      const size_t idx = (size_t)(row0+r)*HD + col;
      float pre = tanhf_fast(acc[i][q] + wxbh[codes_s[r]*HD + col]);
      float zv = zF[idx];
      float hn = (1.f - zv)*hF[idx] + zv*pre;
      hF[idx] = hn;
      hB[idx] = (short)f2bf(hn);
    }
  }
  if (t > 0 && cg == 0 && tt < 64*NNUC){
    int rr = tt/NNUC, j = tt - rr*NNUC;
    int row = row0 + rr;
    float s2 = b_nuc[j];
    #pragma unroll
    for (int s4=0;s4<4;++s4) s2 += nucp[((size_t)s4*NROWS + row)*NNUC + j];
    out_nuc[((size_t)row*LSEQ + (t-1))*NNUC + j] = s2;
  }
}

// ---------------- tail heads: nuc(l=63) + hpn on h(64) ----------------
__global__ __launch_bounds__(512) void heads_k(
    const short* __restrict__ fnuc, const short* __restrict__ fhpn,
    const short* __restrict__ hB,
    const float* __restrict__ latp, const float* __restrict__ w_nuc,
    const float* __restrict__ b_hpn_nl, const float* __restrict__ w_hpn,
    float* __restrict__ nucpH, float* __restrict__ hpnp)
{
  __shared__ __align__(16) short stage[16][4096];
  const int tt = threadIdx.x, l = tt&63, w = tt>>6, lm = l&15, g = l>>4;
  const int rt = blockIdx.x, row0 = rt*32, cg = blockIdx.y;
  const int mat = cg>>2;
  const short* frag = mat ? fhpn : fnuc;
  const int mt = w>>2, ntp = w&3;
  const short* gsrc = frag + ((size_t)((cg&3)*8 + w)*16)*512 + (size_t)l*8;
  #pragma unroll
  for (int kc=0;kc<8;++kc) dma16(gsrc + (size_t)kc*512, &stage[kc][w*512 + l*8]);
  s8b af[16];
  {
    const s8b* hrow = (const s8b*)(hB + (size_t)(row0 + mt*16 + lm)*HD);
    #pragma unroll
    for (int kc=0;kc<16;++kc) af[kc] = hrow[kc*4 + g];
  }
  asm volatile("s_waitcnt vmcnt(0)" ::: "memory");
  __syncthreads();
  #pragma unroll
  for (int kc=8;kc<16;++kc) dma16(gsrc + (size_t)kc*512, &stage[kc][w*512 + l*8]);
  f4 acc[2]; acc[0]=f4zero(); acc[1]=f4zero();
  #pragma unroll
  for (int kc=0;kc<8;++kc){
    #pragma unroll
    for (int i2=0;i2<2;++i2){
      s8b b = ((const s8b*)&stage[kc][(ntp*2+i2)*512])[l];
      acc[i2] = MFMA16(af[kc], b, acc[i2]);
    }
  }
  asm volatile("s_waitcnt vmcnt(0)" ::: "memory");
  __syncthreads();
  #pragma unroll
  for (int kc=8;kc<16;++kc){
    #pragma unroll
    for (int i2=0;i2<2;++i2){
      s8b b = ((const s8b*)&stage[kc][(ntp*2+i2)*512])[l];
      acc[i2] = MFMA16(af[kc], b, acc[i2]);
    }
  }
  const int slab = (cg&3)*4 + ntp;
  if (mat==0){
    float p[4][NNUC];
    #pragma unroll
    for (int q=0;q<4;++q)
      #pragma unroll
      for (int j=0;j<NNUC;++j) p[q][j]=0.f;
    #pragma unroll
    for (int i2=0;i2<2;++i2){
      const int col = (cg&3)*128 + (ntp*2+i2)*16 + lm;
      #pragma unroll
      for (int q=0;q<4;++q){
        const int r = mt*16 + g*4 + q;
        float hid = fmaxf(acc[i2][q] + latp[(size_t)(row0+r)*HD + col], 0.f);
        #pragma unroll
        for (int j=0;j<NNUC;++j) p[q][j] = fmaf(hid, w_nuc[(size_t)j*HD + col], p[q][j]);
      }
    }
    #pragma unroll
    for (int s=1;s<16;s<<=1)
      #pragma unroll
      for (int q=0;q<4;++q)
        #pragma unroll
        for (int j=0;j<NNUC;++j) p[q][j] += __shfl_xor(p[q][j], s);
    if (lm==0){
      #pragma unroll
      for (int q=0;q<4;++q){
        const int row = row0 + mt*16 + g*4 + q;
        #pragma unroll
        for (int j=0;j<NNUC;++j)
          nucpH[((size_t)slab*NROWS + row)*NNUC + j] = p[q][j];
      }
    }
  } else {
    float p[4][NHPN];
    #pragma unroll
    for (int q=0;q<4;++q)
      #pragma unroll
      for (int j=0;j<NHPN;++j) p[q][j]=0.f;
    #pragma unroll
    for (int i2=0;i2<2;++i2){
      const int col = (cg&3)*128 + (ntp*2+i2)*16 + lm;
      float bnl = b_hpn_nl[col];
      #pragma unroll
      for (int q=0;q<4;++q){
        float hid = fmaxf(acc[i2][q] + bnl, 0.f);
        #pragma unroll
        for (int j=0;j<NHPN;++j) p[q][j] = fmaf(hid, w_hpn[(size_t)j*HD + col], p[q][j]);
      }
    }
    #pragma unroll
    for (int s=1;s<16;s<<=1)
      #pragma unroll
      for (int q=0;q<4;++q)
        #pragma unroll
        for (int j=0;j<NHPN;++j) p[q][j] += __shfl_xor(p[q][j], s);
    if (lm==0){
      #pragma unroll
      for (int q=0;q<4;++q){
        const int row = row0 + mt*16 + g*4 + q;
        #pragma unroll
        for (int j=0;j<NHPN;++j)
          hpnp[((size_t)slab*NROWS + row)*NHPN + j] = p[q][j];
      }
    }
  }
}

__global__ void final_red_k(const float* __restrict__ nucpH, const float* __restrict__ hpnp,
    const float* __restrict__ topo_p,
    const float* __restrict__ b_nuc, const float* __restrict__ b_hpn, const float* __restrict__ b_topo,
    const float* __restrict__ hF,
    float* __restrict__ out_newh, float* __restrict__ out_hpn, float* __restrict__ out_nuc,
    float* __restrict__ out_stop)
{
  int gid = blockIdx.x*256 + threadIdx.x;   // grid 128x256 = 32768
  if (gid < NROWS*NNUC){
    int n = gid/NNUC, j = gid - n*NNUC;
    float s = b_nuc[j];
    #pragma unroll
    for (int s8=0;s8<16;++s8) s += nucpH[((size_t)s8*NROWS + n)*NNUC + j];
    out_nuc[((size_t)n*LSEQ + 63)*NNUC + j] = s;
  } else if (gid < NROWS*NNUC + NROWS*NHPN){
    int g2 = gid - NROWS*NNUC;
    int n = g2/NHPN, j = g2 - n*NHPN;
    float s = b_hpn[j];
    #pragma unroll
    for (int s8=0;s8<16;++s8) s += hpnp[((size_t)s8*NROWS + n)*NHPN + j];
    out_hpn[(size_t)n*NHPN + j] = s;
  } else if (gid < NROWS*NNUC + NROWS*NHPN + NROWS){
    int n = gid - (NROWS*NNUC + NROWS*NHPN);
    float s = b_topo[0];
    #pragma unroll
    for (int s16=0;s16<16;++s16) s += topo_p[(size_t)s16*NROWS + n];
    out_stop[n] = s;
  }
  const float4* src = (const float4*)hF;
  float4* dst = (float4*)out_newh;
  for (int i = gid; i < NROWS*HD/4; i += 32768) dst[i] = src[i];
}

// ---------------- host ----------------
extern "C" void kernel_launch(void* const* d_in, const int* in_sizes, int n_in,
                              void* d_out, int out_size, void* d_ws, size_t ws_size,
                              hipStream_t stream_){
  (void)in_sizes; (void)n_in; (void)out_size; (void)ws_size;
  const int*   hpn_idx      = (const int*)d_in[0];
  const int*   nuc_idx      = (const int*)d_in[1];
  const float* h_nei        = (const float*)d_in[2];
  const float* graph_latent = (const float*)d_in[3];
  const float* Wz_mp=(const float*)d_in[4];  const float* bz_mp=(const float*)d_in[5];
  const float* Wr_mp=(const float*)d_in[6];  const float* br_mp=(const float*)d_in[7];
  const float* Ur_mp=(const float*)d_in[8];
  const float* Wh_mp=(const float*)d_in[9];  const float* bh_mp=(const float*)d_in[10];
  const float* Wz_nuc=(const float*)d_in[11]; const float* bz_nuc=(const float*)d_in[12];
  const float* Wr_nuc=(const float*)d_in[13]; const float* br_nuc=(const float*)d_in[14];
  const float* Wh_nuc=(const float*)d_in[15]; const float* bh_nuc=(const float*)d_in[16];
  const float* W_hpn_nl=(const float*)d_in[17]; const float* b_hpn_nl=(const float*)d_in[18];
  const float* W_hpn=(const float*)d_in[19];  const float* b_hpn=(const float*)d_in[20];
  const float* W_nuc_nl=(const float*)d_in[21]; const float* b_nuc_nl=(const float*)d_in[22];
  const float* W_nuc=(const float*)d_in[23];  const float* b_nuc=(const float*)d_in[24];
  const float* W_topo_nl=(const float*)d_in[25]; const float* b_topo_nl=(const float*)d_in[26];
  const float* W_topo=(const float*)d_in[27]; const float* b_topo=(const float*)d_in[28];

  float* ws = (float*)d_ws;
  size_t off = 0;
  auto take = [&](size_t nfl){ float* p = ws + off; off += nfl; return p; };
  float* wt_nl_lat = take((size_t)LATD*HD);
  short* fz    = (short*)take((size_t)HD*HD/2);
  short* fr    = (short*)take((size_t)HD*HD/2);
  short* fh    = (short*)take((size_t)HD*HD/2);
  short* fnuc  = (short*)take((size_t)HD*HD/2);
  short* fhpn  = (short*)take((size_t)HD*HD/2);
  short* fWzh  = (short*)take((size_t)HD*HD/2);
  short* fUr   = (short*)take((size_t)HD*HD/2);
  short* fWhh  = (short*)take((size_t)HD*HD/2);
  short* fWtopo= (short*)take((size_t)HD*HD/2);
  float* wxbz = take((size_t)NNUC*HD);
  float* wxbr = take((size_t)NNUC*HD);
  float* wxbh = take((size_t)NNUC*HD);
  float* wxbz_mp = take((size_t)NHPN*HD);
  float* wxbr_mp = take((size_t)NHPN*HD);
  float* wxbh_mp = take((size_t)NHPN*HD);
  float* latp = take((size_t)NROWS*HD);
  float* hF   = take((size_t)NROWS*HD);
  short* hB   = (short*)take((size_t)NROWS*HD/2);
  short* ghB  = (short*)take((size_t)NROWS*HD/2);
  float* zF   = take((size_t)NROWS*HD);
  float* sumhF = take((size_t)NROWS*HD);
  short* sumhB = (short*)take((size_t)NROWS*HD/2);
  short* sgB   = (short*)take((size_t)NROWS*HD/2);
  short* hnB   = (short*)take((size_t)NROWS*KNEI*HD/2);
  float* nucp = take((size_t)4*NROWS*NNUC);
  float* nucpH= take((size_t)16*NROWS*NNUC);
  float* hpnp = take((size_t)16*NROWS*NHPN);
  float* topo_p = take((size_t)16*NROWS);

  float* out       = (float*)d_out;
  float* out_newh  = out;
  float* out_hpn   = out + (size_t)NROWS*HD;
  float* out_nuc   = out_hpn + (size_t)NROWS*NHPN;
  float* out_stop  = out_nuc + (size_t)NROWS*LSEQ*NNUC;

  transpose_w<<<(LATD*HD+255)/256, 256, 0, stream_>>>(W_nuc_nl, wt_nl_lat, HD+LATD, HD, LATD);

  // fused fragment prep (9 matrices, 1 launch)
  {
    Frag9 fa;
    const float* Ws[9] = {Wz_nuc, Wr_nuc, Wh_nuc, W_nuc_nl, W_hpn_nl, Wz_mp, Ur_mp, Wh_mp, W_topo_nl};
    short* ds[9] = {fz, fr, fh, fnuc, fhpn, fWzh, fUr, fWhh, fWtopo};
    int scs[9] = {HD+NNUC, HD+NNUC, HD+NNUC, HD+LATD, HD, HD+NHPN, HD, HD+NHPN, HD};
    int cos[9] = {NNUC, NNUC, NNUC, 0, 0, NHPN, 0, NHPN, 0};
    for (int i=0;i<9;++i){ fa.W[i]=Ws[i]; fa.dst[i]=ds[i]; fa.sc[i]=scs[i]; fa.co[i]=cos[i]; }
    fragprep9_k<<<9*1024, 256, 0, stream_>>>(fa);
  }
  // fused wxb prep (6 tables, 1 launch)
  {
    Wxb6 wa;
    const float* Ws[6] = {Wz_nuc, Wr_nuc, Wh_nuc, Wz_mp, Wr_mp, Wh_mp};
    const float* bs[6] = {bz_nuc, br_nuc, bh_nuc, bz_mp, br_mp, bh_mp};
    float* ds[6] = {wxbz, wxbr, wxbh, wxbz_mp, wxbr_mp, wxbh_mp};
    int scs[6] = {HD+NNUC, HD+NNUC, HD+NNUC, HD+NHPN, NHPN, HD+NHPN};
    int ncs[6] = {NNUC, NNUC, NNUC, NHPN, NHPN, NHPN};
    for (int i=0;i<6;++i){ wa.W[i]=Ws[i]; wa.b[i]=bs[i]; wa.dst[i]=ds[i]; wa.sc[i]=scs[i]; wa.nc[i]=ncs[i]; }
    wxb6_k<<<60, 256, 0, stream_>>>(wa);
  }

  latp_k<<<NROWS/16, 512, 0, stream_>>>(graph_latent, wt_nl_lat, b_nuc_nl, latp);

  // ---- GraphGRU via MFMA ----
  sumcast_k<<<512, 512, 0, stream_>>>(h_nei, sumhF, sumhB, hnB);
  ggru_gemm_k<<<dim3(64,4), 512, 0, stream_>>>(
      0, fWzh, sumhB, hpn_idx, wxbz_mp, nullptr, nullptr, nullptr,
      zF, nullptr, nullptr, nullptr);
  ggru_r_k<<<dim3(128,4), 512, 0, stream_>>>(fUr, hnB, hpn_idx, wxbr_mp, sgB);
  ggru_gemm_k<<<dim3(64,4), 512, 0, stream_>>>(
      1, fWhh, sgB, hpn_idx, wxbh_mp, sumhF, zF, nullptr,
      nullptr, hF, hB, nullptr);
  ggru_gemm_k<<<dim3(64,4), 512, 0, stream_>>>(
      2, fWtopo, hB, hpn_idx, b_topo_nl, nullptr, nullptr, W_topo,
      nullptr, nullptr, nullptr, topo_p);

  // ---- scan: per-step kernels (cross-CU sync measured at ~50-100us/barrier
  // on this part in rounds 4 & 12 -> 2 launches/step is the cheapest sync) ----
  for (int t = 0; t < LSEQ; ++t){
    zrnuc_k<<<dim3(16,12), 512, 0, stream_>>>(
        t, nuc_idx, fz, fr, fnuc, hB, hF,
        wxbz, wxbr, latp, W_nuc, zF, ghB, nucp);
    cand_k<<<dim3(32,4), 512, 0, stream_>>>(
        t, nuc_idx, fh, ghB, wxbh, zF, hF, hB,
        nucp, b_nuc, out_nuc);
  }

  heads_k<<<dim3(64,8), 512, 0, stream_>>>(
      fnuc, fhpn, hB, latp, W_nuc, b_hpn_nl, W_hpn, nucpH, hpnp);
  final_red_k<<<128, 256, 0, stream_>>>(
      nucpH, hpnp, topo_p, b_nuc, b_hpn, b_topo, hF,
      out_newh, out_hpn, out_nuc, out_stop);
}

// Round 14
// 1769.345 us; speedup vs baseline: 7.3855x; 1.0323x over previous
//
#include <hip/hip_runtime.h>
#include <math.h>

#define NROWS 2048
#define KNEI  8
#define LSEQ  64
#define HD    512
#define HD4   128
#define LATD  128
#define NHPN  4
#define NNUC  5

typedef __attribute__((ext_vector_type(8))) short s8b;   // 8 bf16 (16B)
typedef __attribute__((ext_vector_type(4))) short s4b;   // 4 bf16 (8B)
typedef __attribute__((ext_vector_type(4))) float f4;    // MFMA acc

#define MFMA16(a,b,c) __builtin_amdgcn_mfma_f32_16x16x32_bf16(a,b,c,0,0,0)

__device__ __forceinline__ f4 f4zero(){ f4 z; z[0]=0.f; z[1]=0.f; z[2]=0.f; z[3]=0.f; return z; }
__device__ __forceinline__ float sigf(float x){ return __fdividef(1.0f, 1.0f + __expf(-x)); }
__device__ __forceinline__ float tanhf_fast(float x){
  float e = __expf(-2.0f*fabsf(x));
  float t = __fdividef(1.0f - e, 1.0f + e);
  return x >= 0.f ? t : -t;
}
__device__ __forceinline__ unsigned short f2bf(float x){
  union{float f; unsigned u;} v; v.f = x;
  unsigned r = (v.u + 0x7FFFu + ((v.u>>16)&1u)) >> 16;
  return (unsigned short)r;
}
__device__ __forceinline__ float bf2f(unsigned short u){
  union{unsigned x; float f;} v; v.x = ((unsigned)u)<<16; return v.f;
}
__device__ __forceinline__ void add4(float4& a, float4 b){ a.x+=b.x; a.y+=b.y; a.z+=b.z; a.w+=b.w; }

__device__ __forceinline__ void dma16(const short* g, const short* l){
  __builtin_amdgcn_global_load_lds(
      (const __attribute__((address_space(1))) void*)(unsigned long long)g,
      (__attribute__((address_space(3))) void*)(unsigned long long)l,
      16, 0, 0);
}

// ---------------- prep kernels ----------------

__global__ void transpose_w(const float* __restrict__ src, float* __restrict__ dst,
                            int src_cols, int col_off, int nh){
  int idx = blockIdx.x*256 + threadIdx.x;
  if (idx >= nh*HD) return;
  int h = idx / HD, o = idx - h*HD;
  dst[idx] = src[o*src_cols + col_off + h];
}

// fused 9-matrix B-frag prep: dst[m][tile*512 + l*8 + j] = W[m][row][k]
struct Frag9 {
  const float* W[9];
  short* dst[9];
  int sc[9];
  int co[9];
};
__global__ void fragprep9_k(Frag9 a){
  int bid = blockIdx.x;               // 9*1024 blocks
  int m = bid >> 10;
  int idx = ((bid & 1023) << 8) + threadIdx.x;
  int j = idx&7, l = (idx>>3)&63, tile = idx>>9;
  int kc = tile&15, ot = tile>>4;
  int row = ot*16 + (l&15), k = kc*32 + (l>>4)*8 + j;
  a.dst[m][idx] = (short)f2bf(a.W[m][(size_t)row*a.sc[m] + a.co[m] + k]);
}

// fused 6-table wxb prep: dst[m][c*HD + n] = W[m][n*sc+c] + b[m][n]
struct Wxb6 {
  const float* W[6];
  const float* b[6];
  float* dst[6];
  int sc[6];
  int nc[6];
};
__global__ void wxb6_k(Wxb6 a){
  int m = blockIdx.x / 10;            // 60 blocks (10 per table)
  int idx = (blockIdx.x % 10)*256 + threadIdx.x;
  if (idx >= a.nc[m]*HD) return;
  int c = idx/HD, n = idx - c*HD;
  a.dst[m][idx] = a.W[m][(size_t)n*a.sc[m] + c] + a.b[m][n];
}

// latp[n][o] = b_nl[o] + sum_q gl[n][q]*wtlat[q*HD+o]
__global__ __launch_bounds__(512) void latp_k(const float* __restrict__ gl, const float* __restrict__ wtlat,
                     const float* __restrict__ bnl, float* __restrict__ latp){
  __shared__ float gls[16][LATD];
  int b = blockIdx.x, t = threadIdx.x;
  for (int i=t;i<16*LATD;i+=512) gls[i/LATD][i%LATD] = gl[(size_t)(b*16)*LATD + i];
  __syncthreads();
  float acc[16];
  float bv = bnl[t];
  #pragma unroll
  for (int r=0;r<16;++r) acc[r]=bv;
  for (int q=0;q<LATD;++q){
    float wv = wtlat[(size_t)q*HD + t];
    #pragma unroll
    for (int r=0;r<16;++r) acc[r] = fmaf(gls[r][q], wv, acc[r]);
  }
  #pragma unroll
  for (int r=0;r<16;++r) latp[(size_t)(b*16+r)*HD + t] = acc[r];
}

// sumh = h_nei.sum(k): fp32 + bf16 copies; also bf16 copy of full h_nei (hnB).
__global__ void sumcast_k(const float* __restrict__ h_nei,
                          float* __restrict__ sumhF, short* __restrict__ sumhB,
                          short* __restrict__ hnB){
  int idx = blockIdx.x*512 + threadIdx.x;
  int n = idx >> 7, c4 = idx & 127;
  const float4* hn4 = (const float4*)h_nei;
  size_t base = (size_t)n*KNEI*HD4 + c4;
  float4 s = make_float4(0.f,0.f,0.f,0.f);
  #pragma unroll
  for (int k=0;k<KNEI;++k){
    float4 v = hn4[base + (size_t)k*HD4];
    add4(s, v);
    s4b pb;
    pb[0]=(short)f2bf(v.x); pb[1]=(short)f2bf(v.y); pb[2]=(short)f2bf(v.z); pb[3]=(short)f2bf(v.w);
    ((s4b*)hnB)[(size_t)(n*KNEI + k)*HD4 + c4] = pb;
  }
  ((float4*)sumhF)[(size_t)n*HD4 + c4] = s;
  s4b p;
  p[0]=(short)f2bf(s.x); p[1]=(short)f2bf(s.y); p[2]=(short)f2bf(s.z); p[3]=(short)f2bf(s.w);
  ((s4b*)sumhB)[(size_t)n*HD4 + c4] = p;
}

// ---------------- GraphGRU MFMA GEMMs (unchanged verified) ----------------
__global__ __launch_bounds__(512) void ggru_gemm_k(
    int mode,
    const short* __restrict__ frag,
    const short* __restrict__ A,
    const int* __restrict__ hpn_idx,
    const float* __restrict__ bias_tab,
    const float* __restrict__ sumhF, const float* __restrict__ zF_in,
    const float* __restrict__ w_topo,
    float* __restrict__ zF_out,
    float* __restrict__ hF, short* __restrict__ hB,
    float* __restrict__ topo_p)
{
  __shared__ __align__(16) short stage[16][4096];
  __shared__ int codes_s[32];
  const int tt = threadIdx.x, l = tt&63, w = tt>>6, lm = l&15, g = l>>4;
  const int rt = blockIdx.x, row0 = rt*32, cg = blockIdx.y;
  if (tt<32) codes_s[tt] = hpn_idx[row0+tt];
  const int mt = w>>2, ntp = w&3;
  const short* gsrc = frag + ((size_t)(cg*8 + w)*16)*512 + (size_t)l*8;
  #pragma unroll
  for (int kc=0;kc<8;++kc) dma16(gsrc + (size_t)kc*512, &stage[kc][w*512 + l*8]);
  s8b af[16];
  {
    const s8b* arow = (const s8b*)(A + (size_t)(row0 + mt*16 + lm)*HD);
    #pragma unroll
    for (int kc=0;kc<16;++kc) af[kc] = arow[kc*4 + g];
  }
  asm volatile("s_waitcnt vmcnt(0)" ::: "memory");
  __syncthreads();
  #pragma unroll
  for (int kc=8;kc<16;++kc) dma16(gsrc + (size_t)kc*512, &stage[kc][w*512 + l*8]);
  f4 acc[2]; acc[0]=f4zero(); acc[1]=f4zero();
  #pragma unroll
  for (int kc=0;kc<8;++kc){
    #pragma unroll
    for (int i2=0;i2<2;++i2){
      s8b b = ((const s8b*)&stage[kc][(ntp*2+i2)*512])[l];
      acc[i2] = MFMA16(af[kc], b, acc[i2]);
    }
  }
  asm volatile("s_waitcnt vmcnt(0)" ::: "memory");
  __syncthreads();
  #pragma unroll
  for (int kc=8;kc<16;++kc){
    #pragma unroll
    for (int i2=0;i2<2;++i2){
      s8b b = ((const s8b*)&stage[kc][(ntp*2+i2)*512])[l];
      acc[i2] = MFMA16(af[kc], b, acc[i2]);
    }
  }
  if (mode==0){
    #pragma unroll
    for (int i2=0;i2<2;++i2){
      const int col = cg*128 + (ntp*2+i2)*16 + lm;
      #pragma unroll
      for (int q=0;q<4;++q){
        const int r = mt*16 + g*4 + q;
        zF_out[(size_t)(row0+r)*HD + col] = sigf(acc[i2][q] + bias_tab[codes_s[r]*HD + col]);
      }
    }
  } else if (mode==1){
    #pragma unroll
    for (int i2=0;i2<2;++i2){
      const int col = cg*128 + (ntp*2+i2)*16 + lm;
      #pragma unroll
      for (int q=0;q<4;++q){
        const int r = mt*16 + g*4 + q;
        const size_t idx = (size_t)(row0+r)*HD + col;
        float pre = tanhf_fast(acc[i2][q] + bias_tab[codes_s[r]*HD + col]);
        float zv = zF_in[idx];
        float m = (1.f - zv)*sumhF[idx] + zv*pre;
        hF[idx] = m;
        hB[idx] = (short)f2bf(m);
      }
    }
  } else {
    float p[4];
    #pragma unroll
    for (int q=0;q<4;++q) p[q]=0.f;
    #pragma unroll
    for (int i2=0;i2<2;++i2){
      const int col = cg*128 + (ntp*2+i2)*16 + lm;
      float wv = w_topo[col];
      float bnl = bias_tab[col];
      #pragma unroll
      for (int q=0;q<4;++q){
        float hid = fmaxf(acc[i2][q] + bnl, 0.f);
        p[q] = fmaf(hid, wv, p[q]);
      }
    }
    #pragma unroll
    for (int s=1;s<16;s<<=1)
      #pragma unroll
      for (int q=0;q<4;++q) p[q] += __shfl_xor(p[q], s);
    if (lm==0){
      #pragma unroll
      for (int q=0;q<4;++q)
        topo_p[(size_t)(cg*4+ntp)*NROWS + row0 + mt*16 + g*4 + q] = p[q];
    }
  }
}

// r gate: [16384,512] x Ur^T with in-register k-reduction -> sum_gated bf16.
__global__ __launch_bounds__(512) void ggru_r_k(
    const short* __restrict__ fUr,
    const short* __restrict__ hnB,
    const int* __restrict__ hpn_idx,
    const float* __restrict__ wxbr_mp,
    short* __restrict__ sgB)
{
  __shared__ __align__(16) short stage[16][4096];
  __shared__ int codes_s[16];
  const int tt = threadIdx.x, l = tt&63, w = tt>>6, lm = l&15, g = l>>4;
  const int row0 = blockIdx.x*128, cg = blockIdx.y;
  if (tt<16) codes_s[tt] = hpn_idx[(row0>>3) + tt];
  const short* gsrc = fUr + ((size_t)(cg*8 + w)*16)*512 + (size_t)l*8;
  #pragma unroll
  for (int kc=0;kc<8;++kc) dma16(gsrc + (size_t)kc*512, &stage[kc][w*512 + l*8]);
  s8b af[16];
  {
    const s8b* arow = (const s8b*)(hnB + (size_t)(row0 + w*16 + lm)*HD);
    #pragma unroll
    for (int kc=0;kc<16;++kc) af[kc] = arow[kc*4 + g];
  }
  asm volatile("s_waitcnt vmcnt(0)" ::: "memory");
  __syncthreads();
  #pragma unroll
  for (int kc=8;kc<16;++kc) dma16(gsrc + (size_t)kc*512, &stage[kc][w*512 + l*8]);
  f4 acc[8];
  #pragma unroll
  for (int i=0;i<8;++i) acc[i]=f4zero();
  #pragma unroll
  for (int kc=0;kc<8;++kc){
    #pragma unroll
    for (int ot=0;ot<8;++ot){
      s8b b = ((const s8b*)&stage[kc][ot*512])[l];
      acc[ot] = MFMA16(af[kc], b, acc[ot]);
    }
  }
  asm volatile("s_waitcnt vmcnt(0)" ::: "memory");
  __syncthreads();
  #pragma unroll
  for (int kc=8;kc<16;++kc){
    #pragma unroll
    for (int ot=0;ot<8;++ot){
      s8b b = ((const s8b*)&stage[kc][ot*512])[l];
      acc[ot] = MFMA16(af[kc], b, acc[ot]);
    }
  }
  const int nloc = w*2 + (g>>1);
  const int code = codes_s[nloc];
  #pragma unroll
  for (int ot=0;ot<8;++ot){
    const int col = cg*128 + ot*16 + lm;
    float part = 0.f;
    #pragma unroll
    for (int q=0;q<4;++q){
      const int lr = w*16 + g*4 + q;
      float rv = sigf(acc[ot][q] + wxbr_mp[code*HD + col]);
      part += rv * bf2f((unsigned short)hnB[(size_t)(row0+lr)*HD + col]);
    }
    part += __shfl_xor(part, 16);
    if ((g&1)==0){
      const int node = (row0>>3) + nloc;
      sgB[(size_t)node*HD + col] = (short)f2bf(part);
    }
  }
}

// ---------------- scan step kernel A: counted-vmcnt staging ----------------
// Issue all 16 kc DMAs up-front (groups pinned so phase-B is the newest 8
// VMEM ops), vmcnt(8)+raw barrier -> compute A (B's latency hides under it),
// vmcnt(0)+raw barrier -> compute B.
__global__ __launch_bounds__(512) void zrnuc_k(
    int t, const int* __restrict__ nuc_idx,
    const short* __restrict__ fz, const short* __restrict__ fr, const short* __restrict__ fnuc,
    const short* __restrict__ hB, const float* __restrict__ hF,
    const float* __restrict__ wxbz, const float* __restrict__ wxbr,
    const float* __restrict__ latp, const float* __restrict__ w_nuc,
    unsigned short* __restrict__ zB, short* __restrict__ ghB, float* __restrict__ nucp)
{
  const int cg = blockIdx.y;
  const int mat = cg>>2;
  if (t==0 && mat==2) return;
  __shared__ __align__(16) short stage[16][4096];
  __shared__ int codes_s[128];
  const int tt = threadIdx.x, l = tt&63, w = tt>>6, lm = l&15, g = l>>4;
  const int row0 = blockIdx.x*128;
  const short* frag = (mat==0)?fz:((mat==1)?fr:fnuc);
  const int otb = (cg&3)*8;
  if (tt<128) codes_s[tt] = nuc_idx[(size_t)(row0+tt)*LSEQ + t];
  s8b af[16];
  {
    const s8b* hrow = (const s8b*)(hB + (size_t)(row0 + w*16 + lm)*HD);
    #pragma unroll
    for (int kc=0;kc<16;++kc) af[kc] = hrow[kc*4 + g];
  }
  const short* gsrc = frag + ((size_t)(otb + w)*16)*512 + (size_t)l*8;
  __builtin_amdgcn_sched_barrier(0);
  #pragma unroll
  for (int kc=0;kc<8;++kc) dma16(gsrc + (size_t)kc*512, &stage[kc][w*512 + l*8]);
  __builtin_amdgcn_sched_barrier(0);
  #pragma unroll
  for (int kc=8;kc<16;++kc) dma16(gsrc + (size_t)kc*512, &stage[kc][w*512 + l*8]);
  __builtin_amdgcn_sched_barrier(0);
  asm volatile("s_waitcnt vmcnt(8) lgkmcnt(0)" ::: "memory");
  __builtin_amdgcn_s_barrier();
  __builtin_amdgcn_sched_barrier(0);
  f4 acc[8];
  #pragma unroll
  for (int i=0;i<8;++i) acc[i]=f4zero();
  #pragma unroll
  for (int kc=0;kc<8;++kc){
    #pragma unroll
    for (int ot=0;ot<8;++ot){
      s8b b = ((const s8b*)&stage[kc][ot*512])[l];
      acc[ot] = MFMA16(af[kc], b, acc[ot]);
    }
  }
  asm volatile("s_waitcnt vmcnt(0)" ::: "memory");
  __builtin_amdgcn_s_barrier();
  __builtin_amdgcn_sched_barrier(0);
  #pragma unroll
  for (int kc=8;kc<16;++kc){
    #pragma unroll
    for (int ot=0;ot<8;++ot){
      s8b b = ((const s8b*)&stage[kc][ot*512])[l];
      acc[ot] = MFMA16(af[kc], b, acc[ot]);
    }
  }
  const int colb = (cg&3)*128;
  if (mat==0){
    #pragma unroll
    for (int ot=0;ot<8;++ot){
      const int col = colb + ot*16 + lm;
      #pragma unroll
      for (int q=0;q<4;++q){
        const int r = w*16 + g*4 + q;
        zB[(size_t)(row0+r)*HD + col] = f2bf(sigf(acc[ot][q] + wxbz[codes_s[r]*HD + col]));
      }
    }
  } else if (mat==1){
    #pragma unroll
    for (int ot=0;ot<8;++ot){
      const int col = colb + ot*16 + lm;
      #pragma unroll
      for (int q=0;q<4;++q){
        const int r = w*16 + g*4 + q;
        float rv = sigf(acc[ot][q] + wxbr[codes_s[r]*HD + col]);
        ghB[(size_t)(row0+r)*HD + col] = (short)f2bf(rv * hF[(size_t)(row0+r)*HD + col]);
      }
    }
  } else {
    float p[4][NNUC];
    #pragma unroll
    for (int q=0;q<4;++q)
      #pragma unroll
      for (int j=0;j<NNUC;++j) p[q][j]=0.f;
    #pragma unroll
    for (int ot=0;ot<8;++ot){
      const int col = colb + ot*16 + lm;
      #pragma unroll
      for (int q=0;q<4;++q){
        const int r = w*16 + g*4 + q;
        float hid = fmaxf(acc[ot][q] + latp[(size_t)(row0+r)*HD + col], 0.f);
        #pragma unroll
        for (int j=0;j<NNUC;++j) p[q][j] = fmaf(hid, w_nuc[(size_t)j*HD + col], p[q][j]);
      }
    }
    #pragma unroll
    for (int s=1;s<16;s<<=1)
      #pragma unroll
      for (int q=0;q<4;++q)
        #pragma unroll
        for (int j=0;j<NNUC;++j) p[q][j] += __shfl_xor(p[q][j], s);
    if (lm==0){
      const int slab = cg&3;
      #pragma unroll
      for (int q=0;q<4;++q){
        const int row = row0 + w*16 + g*4 + q;
        #pragma unroll
        for (int j=0;j<NNUC;++j)
          nucp[((size_t)slab*NROWS + row)*NNUC + j] = p[q][j];
      }
    }
  }
}

// ---------------- scan step kernel B: counted-vmcnt staging ----------------
__global__ __launch_bounds__(512) void cand_k(
    int t, const int* __restrict__ nuc_idx,
    const short* __restrict__ fh,
    const short* __restrict__ ghB,
    const float* __restrict__ wxbh,
    const unsigned short* __restrict__ zB, float* __restrict__ hF, short* __restrict__ hB,
    const float* __restrict__ nucp, const float* __restrict__ b_nuc,
    float* __restrict__ out_nuc)
{
  __shared__ __align__(16) short stage[16][4096];
  __shared__ int codes_s[64];
  const int tt = threadIdx.x, l = tt&63, w = tt>>6, lm = l&15, g = l>>4;
  const int row0 = blockIdx.x*64, cg = blockIdx.y;
  if (tt<64) codes_s[tt] = nuc_idx[(size_t)(row0+tt)*LSEQ + t];
  const int mt = w>>1, oth = w&1;
  s8b af[16];
  {
    const s8b* grow = (const s8b*)(ghB + (size_t)(row0 + mt*16 + lm)*HD);
    #pragma unroll
    for (int kc=0;kc<16;++kc) af[kc] = grow[kc*4 + g];
  }
  const short* gsrc = fh + ((size_t)(cg*8 + w)*16)*512 + (size_t)l*8;
  __builtin_amdgcn_sched_barrier(0);
  #pragma unroll
  for (int kc=0;kc<8;++kc) dma16(gsrc + (size_t)kc*512, &stage[kc][w*512 + l*8]);
  __builtin_amdgcn_sched_barrier(0);
  #pragma unroll
  for (int kc=8;kc<16;++kc) dma16(gsrc + (size_t)kc*512, &stage[kc][w*512 + l*8]);
  __builtin_amdgcn_sched_barrier(0);
  asm volatile("s_waitcnt vmcnt(8) lgkmcnt(0)" ::: "memory");
  __builtin_amdgcn_s_barrier();
  __builtin_amdgcn_sched_barrier(0);
  f4 acc[4];
  #pragma unroll
  for (int i=0;i<4;++i) acc[i]=f4zero();
  #pragma unroll
  for (int kc=0;kc<8;++kc){
    #pragma unroll
    for (int i=0;i<4;++i){
      s8b b = ((const s8b*)&stage[kc][(oth*4+i)*512])[l];
      acc[i] = MFMA16(af[kc], b, acc[i]);
    }
  }
  asm volatile("s_waitcnt vmcnt(0)" ::: "memory");
  __builtin_amdgcn_s_barrier();
  __builtin_amdgcn_sched_barrier(0);
  #pragma unroll
  for (int kc=8;kc<16;++kc){
    #pragma unroll
    for (int i=0;i<4;++i){
      s8b b = ((const s8b*)&stage[kc][(oth*4+i)*512])[l];
      acc[i] = MFMA16(af[kc], b, acc[i]);
    }
  }
  #pragma unroll
  for (int i=0;i<4;++i){
    const int col = cg*128 + (oth*4+i)*16 + lm;
    #pragma unroll
    for (int q=0;q<4;++q){
      const int r = mt*16 + g*4 + q;
      const size_t idx = (size_t)(row0+r)*HD + col;
      float pre = tanhf_fast(acc[i][q] + wxbh[codes_s[r]*HD + col]);
      float zv = bf2f(zB[idx]);
      float hn = (1.f - zv)*hF[idx] + zv*pre;
      hF[idx] = hn;
      hB[idx] = (short)f2bf(hn);
    }
  }
  if (t > 0 && cg == 0 && tt < 64*NNUC){
    int rr = tt/NNUC, j = tt - rr*NNUC;
    int row = row0 + rr;
    float s2 = b_nuc[j];
    #pragma unroll
    for (int s4=0;s4<4;++s4) s2 += nucp[((size_t)s4*NROWS + row)*NNUC + j];
    out_nuc[((size_t)row*LSEQ + (t-1))*NNUC + j] = s2;
  }
}

// ---------------- tail heads: nuc(l=63) + hpn on h(64) ----------------
__global__ __launch_bounds__(512) void heads_k(
    const short* __restrict__ fnuc, const short* __restrict__ fhpn,
    const short* __restrict__ hB,
    const float* __restrict__ latp, const float* __restrict__ w_nuc,
    const float* __restrict__ b_hpn_nl, const float* __restrict__ w_hpn,
    float* __restrict__ nucpH, float* __restrict__ hpnp)
{
  __shared__ __align__(16) short stage[16][4096];
  const int tt = threadIdx.x, l = tt&63, w = tt>>6, lm = l&15, g = l>>4;
  const int rt = blockIdx.x, row0 = rt*32, cg = blockIdx.y;
  const int mat = cg>>2;
  const short* frag = mat ? fhpn : fnuc;
  const int mt = w>>2, ntp = w&3;
  const short* gsrc = frag + ((size_t)((cg&3)*8 + w)*16)*512 + (size_t)l*8;
  #pragma unroll
  for (int kc=0;kc<8;++kc) dma16(gsrc + (size_t)kc*512, &stage[kc][w*512 + l*8]);
  s8b af[16];
  {
    const s8b* hrow = (const s8b*)(hB + (size_t)(row0 + mt*16 + lm)*HD);
    #pragma unroll
    for (int kc=0;kc<16;++kc) af[kc] = hrow[kc*4 + g];
  }
  asm volatile("s_waitcnt vmcnt(0)" ::: "memory");
  __syncthreads();
  #pragma unroll
  for (int kc=8;kc<16;++kc) dma16(gsrc + (size_t)kc*512, &stage[kc][w*512 + l*8]);
  f4 acc[2]; acc[0]=f4zero(); acc[1]=f4zero();
  #pragma unroll
  for (int kc=0;kc<8;++kc){
    #pragma unroll
    for (int i2=0;i2<2;++i2){
      s8b b = ((const s8b*)&stage[kc][(ntp*2+i2)*512])[l];
      acc[i2] = MFMA16(af[kc], b, acc[i2]);
    }
  }
  asm volatile("s_waitcnt vmcnt(0)" ::: "memory");
  __syncthreads();
  #pragma unroll
  for (int kc=8;kc<16;++kc){
    #pragma unroll
    for (int i2=0;i2<2;++i2){
      s8b b = ((const s8b*)&stage[kc][(ntp*2+i2)*512])[l];
      acc[i2] = MFMA16(af[kc], b, acc[i2]);
    }
  }
  const int slab = (cg&3)*4 + ntp;
  if (mat==0){
    float p[4][NNUC];
    #pragma unroll
    for (int q=0;q<4;++q)
      #pragma unroll
      for (int j=0;j<NNUC;++j) p[q][j]=0.f;
    #pragma unroll
    for (int i2=0;i2<2;++i2){
      const int col = (cg&3)*128 + (ntp*2+i2)*16 + lm;
      #pragma unroll
      for (int q=0;q<4;++q){
        const int r = mt*16 + g*4 + q;
        float hid = fmaxf(acc[i2][q] + latp[(size_t)(row0+r)*HD + col], 0.f);
        #pragma unroll
        for (int j=0;j<NNUC;++j) p[q][j] = fmaf(hid, w_nuc[(size_t)j*HD + col], p[q][j]);
      }
    }
    #pragma unroll
    for (int s=1;s<16;s<<=1)
      #pragma unroll
      for (int q=0;q<4;++q)
        #pragma unroll
        for (int j=0;j<NNUC;++j) p[q][j] += __shfl_xor(p[q][j], s);
    if (lm==0){
      #pragma unroll
      for (int q=0;q<4;++q){
        const int row = row0 + mt*16 + g*4 + q;
        #pragma unroll
        for (int j=0;j<NNUC;++j)
          nucpH[((size_t)slab*NROWS + row)*NNUC + j] = p[q][j];
      }
    }
  } else {
    float p[4][NHPN];
    #pragma unroll
    for (int q=0;q<4;++q)
      #pragma unroll
      for (int j=0;j<NHPN;++j) p[q][j]=0.f;
    #pragma unroll
    for (int i2=0;i2<2;++i2){
      const int col = (cg&3)*128 + (ntp*2+i2)*16 + lm;
      float bnl = b_hpn_nl[col];
      #pragma unroll
      for (int q=0;q<4;++q){
        float hid = fmaxf(acc[i2][q] + bnl, 0.f);
        #pragma unroll
        for (int j=0;j<NHPN;++j) p[q][j] = fmaf(hid, w_hpn[(size_t)j*HD + col], p[q][j]);
      }
    }
    #pragma unroll
    for (int s=1;s<16;s<<=1)
      #pragma unroll
      for (int q=0;q<4;++q)
        #pragma unroll
        for (int j=0;j<NHPN;++j) p[q][j] += __shfl_xor(p[q][j], s);
    if (lm==0){
      #pragma unroll
      for (int q=0;q<4;++q){
        const int row = row0 + mt*16 + g*4 + q;
        #pragma unroll
        for (int j=0;j<NHPN;++j)
          hpnp[((size_t)slab*NROWS + row)*NHPN + j] = p[q][j];
      }
    }
  }
}

__global__ void final_red_k(const float* __restrict__ nucpH, const float* __restrict__ hpnp,
    const float* __restrict__ topo_p,
    const float* __restrict__ b_nuc, const float* __restrict__ b_hpn, const float* __restrict__ b_topo,
    const float* __restrict__ hF,
    float* __restrict__ out_newh, float* __restrict__ out_hpn, float* __restrict__ out_nuc,
    float* __restrict__ out_stop)
{
  int gid = blockIdx.x*256 + threadIdx.x;   // grid 128x256 = 32768
  if (gid < NROWS*NNUC){
    int n = gid/NNUC, j = gid - n*NNUC;
    float s = b_nuc[j];
    #pragma unroll
    for (int s8=0;s8<16;++s8) s += nucpH[((size_t)s8*NROWS + n)*NNUC + j];
    out_nuc[((size_t)n*LSEQ + 63)*NNUC + j] = s;
  } else if (gid < NROWS*NNUC + NROWS*NHPN){
    int g2 = gid - NROWS*NNUC;
    int n = g2/NHPN, j = g2 - n*NHPN;
    float s = b_hpn[j];
    #pragma unroll
    for (int s8=0;s8<16;++s8) s += hpnp[((size_t)s8*NROWS + n)*NHPN + j];
    out_hpn[(size_t)n*NHPN + j] = s;
  } else if (gid < NROWS*NNUC + NROWS*NHPN + NROWS){
    int n = gid - (NROWS*NNUC + NROWS*NHPN);
    float s = b_topo[0];
    #pragma unroll
    for (int s16=0;s16<16;++s16) s += topo_p[(size_t)s16*NROWS + n];
    out_stop[n] = s;
  }
  const float4* src = (const float4*)hF;
  float4* dst = (float4*)out_newh;
  for (int i = gid; i < NROWS*HD/4; i += 32768) dst[i] = src[i];
}

// ---------------- host ----------------
extern "C" void kernel_launch(void* const* d_in, const int* in_sizes, int n_in,
                              void* d_out, int out_size, void* d_ws, size_t ws_size,
                              hipStream_t stream_){
  (void)in_sizes; (void)n_in; (void)out_size; (void)ws_size;
  const int*   hpn_idx      = (const int*)d_in[0];
  const int*   nuc_idx      = (const int*)d_in[1];
  const float* h_nei        = (const float*)d_in[2];
  const float* graph_latent = (const float*)d_in[3];
  const float* Wz_mp=(const float*)d_in[4];  const float* bz_mp=(const float*)d_in[5];
  const float* Wr_mp=(const float*)d_in[6];  const float* br_mp=(const float*)d_in[7];
  const float* Ur_mp=(const float*)d_in[8];
  const float* Wh_mp=(const float*)d_in[9];  const float* bh_mp=(const float*)d_in[10];
  const float* Wz_nuc=(const float*)d_in[11]; const float* bz_nuc=(const float*)d_in[12];
  const float* Wr_nuc=(const float*)d_in[13]; const float* br_nuc=(const float*)d_in[14];
  const float* Wh_nuc=(const float*)d_in[15]; const float* bh_nuc=(const float*)d_in[16];
  const float* W_hpn_nl=(const float*)d_in[17]; const float* b_hpn_nl=(const float*)d_in[18];
  const float* W_hpn=(const float*)d_in[19];  const float* b_hpn=(const float*)d_in[20];
  const float* W_nuc_nl=(const float*)d_in[21]; const float* b_nuc_nl=(const float*)d_in[22];
  const float* W_nuc=(const float*)d_in[23];  const float* b_nuc=(const float*)d_in[24];
  const float* W_topo_nl=(const float*)d_in[25]; const float* b_topo_nl=(const float*)d_in[26];
  const float* W_topo=(const float*)d_in[27]; const float* b_topo=(const float*)d_in[28];

  float* ws = (float*)d_ws;
  size_t off = 0;
  auto take = [&](size_t nfl){ float* p = ws + off; off += nfl; return p; };
  float* wt_nl_lat = take((size_t)LATD*HD);
  short* fz    = (short*)take((size_t)HD*HD/2);
  short* fr    = (short*)take((size_t)HD*HD/2);
  short* fh    = (short*)take((size_t)HD*HD/2);
  short* fnuc  = (short*)take((size_t)HD*HD/2);
  short* fhpn  = (short*)take((size_t)HD*HD/2);
  short* fWzh  = (short*)take((size_t)HD*HD/2);
  short* fUr   = (short*)take((size_t)HD*HD/2);
  short* fWhh  = (short*)take((size_t)HD*HD/2);
  short* fWtopo= (short*)take((size_t)HD*HD/2);
  float* wxbz = take((size_t)NNUC*HD);
  float* wxbr = take((size_t)NNUC*HD);
  float* wxbh = take((size_t)NNUC*HD);
  float* wxbz_mp = take((size_t)NHPN*HD);
  float* wxbr_mp = take((size_t)NHPN*HD);
  float* wxbh_mp = take((size_t)NHPN*HD);
  float* latp = take((size_t)NROWS*HD);
  float* hF   = take((size_t)NROWS*HD);
  short* hB   = (short*)take((size_t)NROWS*HD/2);
  short* ghB  = (short*)take((size_t)NROWS*HD/2);
  float* zF   = take((size_t)NROWS*HD);                     // graphgru z (fp32)
  unsigned short* zB = (unsigned short*)take((size_t)NROWS*HD/2);  // scan z (bf16)
  float* sumhF = take((size_t)NROWS*HD);
  short* sumhB = (short*)take((size_t)NROWS*HD/2);
  short* sgB   = (short*)take((size_t)NROWS*HD/2);
  short* hnB   = (short*)take((size_t)NROWS*KNEI*HD/2);
  float* nucp = take((size_t)4*NROWS*NNUC);
  float* nucpH= take((size_t)16*NROWS*NNUC);
  float* hpnp = take((size_t)16*NROWS*NHPN);
  float* topo_p = take((size_t)16*NROWS);

  float* out       = (float*)d_out;
  float* out_newh  = out;
  float* out_hpn   = out + (size_t)NROWS*HD;
  float* out_nuc   = out_hpn + (size_t)NROWS*NHPN;
  float* out_stop  = out_nuc + (size_t)NROWS*LSEQ*NNUC;

  transpose_w<<<(LATD*HD+255)/256, 256, 0, stream_>>>(W_nuc_nl, wt_nl_lat, HD+LATD, HD, LATD);

  // fused fragment prep (9 matrices, 1 launch)
  {
    Frag9 fa;
    const float* Ws[9] = {Wz_nuc, Wr_nuc, Wh_nuc, W_nuc_nl, W_hpn_nl, Wz_mp, Ur_mp, Wh_mp, W_topo_nl};
    short* ds[9] = {fz, fr, fh, fnuc, fhpn, fWzh, fUr, fWhh, fWtopo};
    int scs[9] = {HD+NNUC, HD+NNUC, HD+NNUC, HD+LATD, HD, HD+NHPN, HD, HD+NHPN, HD};
    int cos[9] = {NNUC, NNUC, NNUC, 0, 0, NHPN, 0, NHPN, 0};
    for (int i=0;i<9;++i){ fa.W[i]=Ws[i]; fa.dst[i]=ds[i]; fa.sc[i]=scs[i]; fa.co[i]=cos[i]; }
    fragprep9_k<<<9*1024, 256, 0, stream_>>>(fa);
  }
  // fused wxb prep (6 tables, 1 launch)
  {
    Wxb6 wa;
    const float* Ws[6] = {Wz_nuc, Wr_nuc, Wh_nuc, Wz_mp, Wr_mp, Wh_mp};
    const float* bs[6] = {bz_nuc, br_nuc, bh_nuc, bz_mp, br_mp, bh_mp};
    float* ds[6] = {wxbz, wxbr, wxbh, wxbz_mp, wxbr_mp, wxbh_mp};
    int scs[6] = {HD+NNUC, HD+NNUC, HD+NNUC, HD+NHPN, NHPN, HD+NHPN};
    int ncs[6] = {NNUC, NNUC, NNUC, NHPN, NHPN, NHPN};
    for (int i=0;i<6;++i){ wa.W[i]=Ws[i]; wa.b[i]=bs[i]; wa.dst[i]=ds[i]; wa.sc[i]=scs[i]; wa.nc[i]=ncs[i]; }
    wxb6_k<<<60, 256, 0, stream_>>>(wa);
  }

  latp_k<<<NROWS/16, 512, 0, stream_>>>(graph_latent, wt_nl_lat, b_nuc_nl, latp);

  // ---- GraphGRU via MFMA ----
  sumcast_k<<<512, 512, 0, stream_>>>(h_nei, sumhF, sumhB, hnB);
  ggru_gemm_k<<<dim3(64,4), 512, 0, stream_>>>(
      0, fWzh, sumhB, hpn_idx, wxbz_mp, nullptr, nullptr, nullptr,
      zF, nullptr, nullptr, nullptr);
  ggru_r_k<<<dim3(128,4), 512, 0, stream_>>>(fUr, hnB, hpn_idx, wxbr_mp, sgB);
  ggru_gemm_k<<<dim3(64,4), 512, 0, stream_>>>(
      1, fWhh, sgB, hpn_idx, wxbh_mp, sumhF, zF, nullptr,
      nullptr, hF, hB, nullptr);
  ggru_gemm_k<<<dim3(64,4), 512, 0, stream_>>>(
      2, fWtopo, hB, hpn_idx, b_topo_nl, nullptr, nullptr, W_topo,
      nullptr, nullptr, nullptr, topo_p);

  // ---- scan: per-step kernels (device-side sync measured 10-20x worse) ----
  for (int t = 0; t < LSEQ; ++t){
    zrnuc_k<<<dim3(16,12), 512, 0, stream_>>>(
        t, nuc_idx, fz, fr, fnuc, hB, hF,
        wxbz, wxbr, latp, W_nuc, zB, ghB, nucp);
    cand_k<<<dim3(32,4), 512, 0, stream_>>>(
        t, nuc_idx, fh, ghB, wxbh, zB, hF, hB,
        nucp, b_nuc, out_nuc);
  }

  heads_k<<<dim3(64,8), 512, 0, stream_>>>(
      fnuc, fhpn, hB, latp, W_nuc, b_hpn_nl, W_hpn, nucpH, hpnp);
  final_red_k<<<128, 256, 0, stream_>>>(
      nucpH, hpnp, topo_p, b_nuc, b_hpn, b_topo, hF,
      out_newh, out_hpn, out_nuc, out_stop);
}